// Round 1
// baseline (1290.838 us; speedup 1.0000x reference)
//
#include <hip/hip_runtime.h>
#include <math.h>

#define NN 20000
#define EE 320000
#define NBINS 2048
#define HRANGE 64.0f
#define EPSF 1e-20f

// ---------------- workspace layout (element offsets, all 16B-aligned) ------
constexpr size_t OFF_DEG  = 0;                          // N ints
constexpr size_t OFF_RS   = OFF_DEG + NN;               // N+1 ints (+pad)
constexpr size_t OFF_CUR  = OFF_RS + NN + 8;            // N ints
constexpr size_t OFF_EIX  = OFF_CUR + NN;               // E ints
constexpr size_t OFF_T    = OFF_EIX + EE;               // N*128 f
constexpr size_t OFF_H    = OFF_T + (size_t)NN * 128;   // N*128 f
constexpr size_t OFF_PA   = OFF_H + (size_t)NN * 128;   // N*512 f
constexpr size_t OFF_PB   = OFF_PA + (size_t)NN * 512;  // N*512 f
constexpr size_t OFF_PE   = OFF_PB + (size_t)NN * 512;  // E f
constexpr size_t OFF_DL   = OFF_PE + EE;                // E f
constexpr size_t OFF_TT   = OFF_DL + EE;                // E f
constexpr size_t OFF_HIST = OFF_TT + EE;                // 2*NBINS f
constexpr size_t OFF_SCAL = OFF_HIST + 2 * NBINS;       // 32 f
constexpr size_t OFF_REP  = OFF_SCAL + 32;              // 128 f

__device__ __forceinline__ unsigned ordf(float f) {
  unsigned b = __float_as_uint(f);
  return (b >> 31) ? ~b : (b | 0x80000000u);
}
__device__ __forceinline__ float unordf(unsigned u) {
  unsigned b = (u >> 31) ? (u ^ 0x80000000u) : ~u;
  return __uint_as_float(b);
}

// ---------------- init ------------------------------------------------------
__global__ void init_ws(int* deg, int* cur, float* hist, float* scal, float* rep) {
  int i = blockIdx.x * blockDim.x + threadIdx.x;
  if (i < NN) { deg[i] = 0; cur[i] = 0; }
  if (i < 2 * NBINS) hist[i] = 0.f;
  if (i < 128) rep[i] = 0.f;
  if (i < 32) {
    if (i == 2)      ((unsigned*)scal)[2] = 0xFFFFFFFFu;  // ordered-min init
    else if (i == 3) ((unsigned*)scal)[3] = 0u;           // ordered-max init
    else scal[i] = 0.f;
  }
}

// ---------------- CSR build -------------------------------------------------
__global__ void count_deg(const int* __restrict__ dst, int* __restrict__ deg) {
  int e = blockIdx.x * 256 + threadIdx.x;
  if (e < EE) atomicAdd(&deg[dst[e]], 1);
}

__global__ void scan_deg(const int* __restrict__ deg, int* __restrict__ rs) {
  __shared__ int s[1024];
  __shared__ int carry;
  int tid = threadIdx.x;
  if (tid == 0) carry = 0;
  __syncthreads();
  for (int base = 0; base < NN; base += 1024) {
    int idx = base + tid;
    int v = (idx < NN) ? deg[idx] : 0;
    s[tid] = v;
    __syncthreads();
    for (int off = 1; off < 1024; off <<= 1) {
      int t = (tid >= off) ? s[tid - off] : 0;
      __syncthreads();
      s[tid] += t;
      __syncthreads();
    }
    if (idx < NN) rs[idx] = carry + s[tid] - v;
    __syncthreads();
    if (tid == 1023) carry += s[1023];
    __syncthreads();
  }
  if (tid == 0) rs[NN] = carry;
}

__global__ void fill_csr(const int* __restrict__ dst, const int* __restrict__ rs,
                         int* __restrict__ cur, int* __restrict__ eidx) {
  int e = blockIdx.x * 256 + threadIdx.x;
  if (e < EE) {
    int d = dst[e];
    int p = atomicAdd(&cur[d], 1);
    eidx[rs[d] + p] = e;
  }
}

// ---------------- GIN aggregation: out[n] = x[n] + sum att_e * x[src_e] -----
template <int C>
__global__ __launch_bounds__(256) void aggregate(
    const float* __restrict__ X, float* __restrict__ out,
    const int* __restrict__ src, const int* __restrict__ rs,
    const int* __restrict__ eidx, const float* __restrict__ att) {
  const int lane = threadIdx.x & 63;
  const int n = blockIdx.x * 4 + (threadIdx.x >> 6);
  if (n >= NN) return;
  const int e0 = rs[n], e1 = rs[n + 1];
  if (C == 64) {
    float a = X[(size_t)n * 64 + lane];
    for (int i = e0; i < e1; ++i) {
      int e = eidx[i];
      float w = att ? att[e] : 1.0f;
      a = fmaf(w, X[(size_t)src[e] * 64 + lane], a);
    }
    out[(size_t)n * 64 + lane] = a;
  } else {
    const float2* X2 = (const float2*)X;
    float2 a = X2[(size_t)n * 64 + lane];
    for (int i = e0; i < e1; ++i) {
      int e = eidx[i];
      float w = att ? att[e] : 1.0f;
      float2 v = X2[(size_t)src[e] * 64 + lane];
      a.x = fmaf(w, v.x, a.x);
      a.y = fmaf(w, v.y, a.y);
    }
    ((float2*)out)[(size_t)n * 64 + lane] = a;
  }
}

// ---------------- fp32 GEMM: C = [relu]( A(MxK) @ B(KxBN tile) [+bias] ) ----
template <bool BIAS, bool RELU>
__global__ __launch_bounds__(256) void gemm_k(
    const float* __restrict__ A, const float* __restrict__ B,
    const float* __restrict__ bias, float* __restrict__ C,
    int M, int K, int ldb, int ldc) {
  __shared__ float As[64][33];   // +1 pad: kill bank conflicts on column reads
  __shared__ float Bs[32][128];
  const int tid = threadIdx.x;
  const int row0 = blockIdx.y * 64;
  const int col0 = blockIdx.x * 128;
  const int tr = tid >> 4, tc = tid & 15;
  float acc[4][8];
#pragma unroll
  for (int i = 0; i < 4; i++)
#pragma unroll
    for (int j = 0; j < 8; j++) acc[i][j] = 0.f;

  for (int k0 = 0; k0 < K; k0 += 32) {
    {
      int lin = tid * 8;
      int r = lin >> 5, c = lin & 31;
      float4 v0 = {0, 0, 0, 0}, v1 = {0, 0, 0, 0};
      if (row0 + r < M) {
        const float4* ap = (const float4*)(A + (size_t)(row0 + r) * K + k0 + c);
        v0 = ap[0]; v1 = ap[1];
      }
      As[r][c + 0] = v0.x; As[r][c + 1] = v0.y; As[r][c + 2] = v0.z; As[r][c + 3] = v0.w;
      As[r][c + 4] = v1.x; As[r][c + 5] = v1.y; As[r][c + 6] = v1.z; As[r][c + 7] = v1.w;
    }
    {
      int lin = tid * 16;
      int r = lin >> 7, c = lin & 127;
      const float4* bp = (const float4*)(B + (size_t)(k0 + r) * ldb + col0 + c);
      float4 v0 = bp[0], v1 = bp[1], v2 = bp[2], v3 = bp[3];
      float4* q = (float4*)&Bs[r][c];
      q[0] = v0; q[1] = v1; q[2] = v2; q[3] = v3;
    }
    __syncthreads();
#pragma unroll
    for (int kk = 0; kk < 32; kk++) {
      float a0 = As[tr * 4 + 0][kk], a1 = As[tr * 4 + 1][kk];
      float a2 = As[tr * 4 + 2][kk], a3 = As[tr * 4 + 3][kk];
      float4 b0 = *(const float4*)&Bs[kk][tc * 8];
      float4 b1 = *(const float4*)&Bs[kk][tc * 8 + 4];
      float bv[8] = {b0.x, b0.y, b0.z, b0.w, b1.x, b1.y, b1.z, b1.w};
#pragma unroll
      for (int j = 0; j < 8; j++) {
        acc[0][j] = fmaf(a0, bv[j], acc[0][j]);
        acc[1][j] = fmaf(a1, bv[j], acc[1][j]);
        acc[2][j] = fmaf(a2, bv[j], acc[2][j]);
        acc[3][j] = fmaf(a3, bv[j], acc[3][j]);
      }
    }
    __syncthreads();
  }
#pragma unroll
  for (int i = 0; i < 4; i++) {
    int r = row0 + tr * 4 + i;
    if (r < M) {
#pragma unroll
      for (int j = 0; j < 8; j++) {
        float v = acc[i][j];
        if (BIAS) v += bias[col0 + tc * 8 + j];
        if (RELU) v = fmaxf(v, 0.f);
        C[(size_t)r * ldc + col0 + tc * 8 + j] = v;
      }
    }
  }
}

// ---------------- per-edge pe = w2 . relu(Pa[src] + Pb[dst]) + b2 -----------
__global__ __launch_bounds__(256) void edge_pe(
    const float* __restrict__ Pa, const float* __restrict__ Pb,
    const int* __restrict__ src, const int* __restrict__ dst,
    const float* __restrict__ W2, const float* __restrict__ b2,
    float* __restrict__ pe) {
  const int lane = threadIdx.x & 63;
  const int gw = (blockIdx.x * 256 + threadIdx.x) >> 6;
  const int nw = (gridDim.x * 256) >> 6;
  const float b2v = b2[0];
  const float4* w2v = (const float4*)(W2 + lane * 8);
  float4 w0 = w2v[0], w1 = w2v[1];
  for (int e = gw; e < EE; e += nw) {
    int s = src[e], d = dst[e];
    const float4* pa = (const float4*)(Pa + (size_t)s * 512 + lane * 8);
    const float4* pb = (const float4*)(Pb + (size_t)d * 512 + lane * 8);
    float4 a0 = pa[0], a1 = pa[1];
    float4 c0 = pb[0], c1 = pb[1];
    float acc;
    acc  = fmaxf(a0.x + c0.x, 0.f) * w0.x;
    acc += fmaxf(a0.y + c0.y, 0.f) * w0.y;
    acc += fmaxf(a0.z + c0.z, 0.f) * w0.z;
    acc += fmaxf(a0.w + c0.w, 0.f) * w0.w;
    acc += fmaxf(a1.x + c1.x, 0.f) * w1.x;
    acc += fmaxf(a1.y + c1.y, 0.f) * w1.y;
    acc += fmaxf(a1.z + c1.z, 0.f) * w1.z;
    acc += fmaxf(a1.w + c1.w, 0.f) * w1.w;
#pragma unroll
    for (int off = 32; off; off >>= 1) acc += __shfl_xor(acc, off);
    if (lane == 0) pe[e] = acc + b2v;
  }
}

// ---------------- pe statistics (sum, sumsq, min, max) ----------------------
__global__ __launch_bounds__(256) void pe_stats(const float* __restrict__ pe,
                                                float* __restrict__ scal) {
  __shared__ float r1[256], r2[256], r3[256], r4[256];
  int tid = threadIdx.x;
  float s = 0.f, q = 0.f, mn = 3.0e38f, mx = -3.0e38f;
  for (int i = blockIdx.x * 256 + tid; i < EE; i += gridDim.x * 256) {
    float v = pe[i];
    s += v; q = fmaf(v, v, q);
    mn = fminf(mn, v); mx = fmaxf(mx, v);
  }
  r1[tid] = s; r2[tid] = q; r3[tid] = mn; r4[tid] = mx;
  __syncthreads();
  for (int k = 128; k > 0; k >>= 1) {
    if (tid < k) {
      r1[tid] += r1[tid + k];
      r2[tid] += r2[tid + k];
      r3[tid] = fminf(r3[tid], r3[tid + k]);
      r4[tid] = fmaxf(r4[tid], r4[tid + k]);
    }
    __syncthreads();
  }
  if (tid == 0) {
    unsafeAtomicAdd(&scal[0], r1[0]);
    unsafeAtomicAdd(&scal[1], r2[0]);
    atomicMin((unsigned*)scal + 2, ordf(r3[0]));
    atomicMax((unsigned*)scal + 3, ordf(r4[0]));
  }
}

// ---------------- delta computation + histogram -----------------------------
// delta_e = 2*(atts_e + g_e) - (s_min + s_max); hist of (count, sum delta)
__global__ __launch_bounds__(256) void edge_delta_hist(
    const float* __restrict__ pe, const float* __restrict__ u,
    float* __restrict__ delta, float* __restrict__ hist,
    const float* __restrict__ scal) {
  __shared__ float cnt_s[NBINS], sum_s[NBINS];
  for (int b = threadIdx.x; b < NBINS; b += 256) { cnt_s[b] = 0.f; sum_s[b] = 0.f; }
  float sum = scal[0], ssq = scal[1];
  float mn = unordf(((const unsigned*)scal)[2]);
  float mx = unordf(((const unsigned*)scal)[3]);
  float mu = sum / (float)EE;
  float var = (ssq - sum * sum / (float)EE) / (float)(EE - 1);
  float istd = rsqrtf(fmaxf(var, 1e-30f));
  float shift = (mn - mu) * istd + (mx - mu) * istd;  // s_min + s_max
  __syncthreads();
  for (int e = blockIdx.x * 256 + threadIdx.x; e < EE; e += gridDim.x * 256) {
    float atts = (pe[e] - mu) * istd;
    float g = -logf(-logf(u[e] + EPSF) + EPSF);
    float dl = 2.0f * (atts + g) - shift;
    delta[e] = dl;
    float dcl = fminf(fmaxf(dl, -HRANGE), HRANGE * 0.9999f);
    int b = (int)((dcl + HRANGE) * ((float)NBINS / (2.0f * HRANGE)));
    b = min(max(b, 0), NBINS - 1);
    atomicAdd(&cnt_s[b], 1.0f);
    atomicAdd(&sum_s[b], dcl);
  }
  __syncthreads();
  for (int b = threadIdx.x; b < NBINS; b += 256) {
    float c = cnt_s[b];
    if (c != 0.f) {
      unsafeAtomicAdd(&hist[b], c);
      unsafeAtomicAdd(&hist[NBINS + b], sum_s[b]);
    }
  }
}

// ---------------- Sinkhorn scalar recursion over histogram ------------------
__global__ __launch_bounds__(256) void sinkhorn_iter(const float* __restrict__ hist,
                                                     float* __restrict__ scal) {
  __shared__ float red[256];
  int tid = threadIdx.x;
  float cnt[NBINS / 256], mean[NBINS / 256];
#pragma unroll
  for (int i = 0; i < NBINS / 256; i++) {
    int b = tid + i * 256;
    float c = hist[b];
    cnt[i] = c;
    mean[i] = (c > 0.f) ? hist[NBINS + b] / c : 0.f;
  }
  const float LRD = -1.0986122886681098f;  // log(r1/r0) = log(1/3)
  float S = 0.f, Zfin = 0.f;
  for (int it = 0; it < 30; ++it) {
    float p = 0.f;
#pragma unroll
    for (int i = 0; i < NBINS / 256; i++)
      if (cnt[i] > 0.f) p += cnt[i] / (1.f + expf(-(mean[i] + S)));
    red[tid] = p;
    __syncthreads();
    for (int k = 128; k > 0; k >>= 1) {
      if (tid < k) red[tid] += red[tid + k];
      __syncthreads();
    }
    float Z = red[0];
    __syncthreads();
    if (it < 29)
      S += logf(fmaxf((float)EE - Z, 1.0f)) - logf(Z) + LRD;
    else
      Zfin = Z;
  }
  if (tid == 0) {
    scal[8] = S;
    scal[9] = ((float)EE * 0.25f) / Zfin;  // exp(lr1)/Z_final
  }
}

// ---------------- T_e = scaleT * sigmoid(delta_e + S) -----------------------
__global__ void compute_T(const float* __restrict__ delta,
                          const float* __restrict__ scal,
                          float* __restrict__ Ta) {
  int i = blockIdx.x * 256 + threadIdx.x;
  if (i >= EE) return;
  float S = scal[8], sc = scal[9];
  Ta[i] = sc / (1.f + expf(-(delta[i] + S)));
}

// ---------------- mean pooling + head ---------------------------------------
__global__ __launch_bounds__(128) void col_mean(const float* __restrict__ Hc,
                                                float* __restrict__ rep) {
  int c = threadIdx.x;  // 128
  float p = 0.f;
  for (int n = blockIdx.x; n < NN; n += gridDim.x) p += Hc[(size_t)n * 128 + c];
  unsafeAtomicAdd(&rep[c], p);
}

__global__ __launch_bounds__(128) void head_kernel(const float* __restrict__ repsum,
                                                   const float* __restrict__ hW,
                                                   const float* __restrict__ hb,
                                                   float* __restrict__ out) {
  __shared__ float rep[128];
  int tid = threadIdx.x;
  if (tid < 128) rep[tid] = repsum[tid] * (1.0f / (float)NN);
  __syncthreads();
  if (tid < 10) {
    float a = hb[tid];
#pragma unroll
    for (int c = 0; c < 128; c++) a = fmaf(rep[c], hW[c * 10 + tid], a);
    out[tid] = a;
  }
}

// ---------------- launch ----------------------------------------------------
extern "C" void kernel_launch(void* const* d_in, const int* in_sizes, int n_in,
                              void* d_out, int out_size, void* d_ws, size_t ws_size,
                              hipStream_t stream) {
  const float* x      = (const float*)d_in[0];
  const int*   ei     = (const int*)d_in[1];
  const float* u      = (const float*)d_in[2];
  const float* enc_W0 = (const float*)d_in[3];
  const float* enc_b0 = (const float*)d_in[4];
  const float* enc_W  = (const float*)d_in[5];
  const float* enc_b  = (const float*)d_in[6];
  const float* ea_W1  = (const float*)d_in[7];
  const float* ea_b1  = (const float*)d_in[8];
  const float* ea_W2  = (const float*)d_in[9];
  const float* ea_b2  = (const float*)d_in[10];
  const float* cls_W0 = (const float*)d_in[11];
  const float* cls_b0 = (const float*)d_in[12];
  const float* cls_W  = (const float*)d_in[13];
  const float* cls_b  = (const float*)d_in[14];
  const float* head_W = (const float*)d_in[15];
  const float* head_b = (const float*)d_in[16];
  const int* src  = ei;
  const int* dstp = ei + EE;

  float* wsF = (float*)d_ws;
  int*   wsI = (int*)d_ws;
  int* deg = wsI + OFF_DEG;
  int* rs  = wsI + OFF_RS;
  int* cur = wsI + OFF_CUR;
  int* eix = wsI + OFF_EIX;
  float* tb   = wsF + OFF_T;
  float* Hb   = wsF + OFF_H;
  float* Pa   = wsF + OFF_PA;
  float* Pb   = wsF + OFF_PB;
  float* pe   = wsF + OFF_PE;
  float* dl   = wsF + OFF_DL;
  float* Ta   = wsF + OFF_TT;
  float* hist = wsF + OFF_HIST;
  float* scal = wsF + OFF_SCAL;
  float* rep  = wsF + OFF_REP;
  float* out = (float*)d_out;

  init_ws<<<(NN + 255) / 256, 256, 0, stream>>>(deg, cur, hist, scal, rep);
  count_deg<<<(EE + 255) / 256, 256, 0, stream>>>(dstp, deg);
  scan_deg<<<1, 1024, 0, stream>>>(deg, rs);
  fill_csr<<<(EE + 255) / 256, 256, 0, stream>>>(dstp, rs, cur, eix);

  dim3 g1(1, (NN + 63) / 64);
  dim3 g4(4, (NN + 63) / 64);

  // encoder GIN stack (att = 1)
  aggregate<64><<<(NN + 3) / 4, 256, 0, stream>>>(x, tb, src, rs, eix, nullptr);
  gemm_k<true, true><<<g1, 256, 0, stream>>>(tb, enc_W0, enc_b0, Hb, NN, 64, 128, 128);
  for (int l = 0; l < 4; l++) {
    aggregate<128><<<(NN + 3) / 4, 256, 0, stream>>>(Hb, tb, src, rs, eix, nullptr);
    gemm_k<true, true><<<g1, 256, 0, stream>>>(tb, enc_W + (size_t)l * 128 * 128,
                                               enc_b + (size_t)l * 128, Hb, NN, 128, 128, 128);
  }

  // edge MLP, factorized: Pa = H@W1a + b1, Pb = H@W1b
  gemm_k<true, false><<<g4, 256, 0, stream>>>(Hb, ea_W1, ea_b1, Pa, NN, 128, 512, 512);
  gemm_k<false, false><<<g4, 256, 0, stream>>>(Hb, ea_W1 + 128 * 512, nullptr, Pb, NN, 128, 512, 512);
  edge_pe<<<8192, 256, 0, stream>>>(Pa, Pb, src, dstp, ea_W2, ea_b2, pe);

  // standardize + gumbel + delta + histogram, then scalar Sinkhorn, then T
  pe_stats<<<512, 256, 0, stream>>>(pe, scal);
  edge_delta_hist<<<128, 256, 0, stream>>>(pe, u, dl, hist, scal);
  sinkhorn_iter<<<1, 256, 0, stream>>>(hist, scal);
  compute_T<<<(EE + 255) / 256, 256, 0, stream>>>(dl, scal, Ta);

  // classifier GIN stack (att = T)
  aggregate<64><<<(NN + 3) / 4, 256, 0, stream>>>(x, tb, src, rs, eix, Ta);
  gemm_k<true, true><<<g1, 256, 0, stream>>>(tb, cls_W0, cls_b0, Hb, NN, 64, 128, 128);
  for (int l = 0; l < 4; l++) {
    aggregate<128><<<(NN + 3) / 4, 256, 0, stream>>>(Hb, tb, src, rs, eix, Ta);
    gemm_k<true, true><<<g1, 256, 0, stream>>>(tb, cls_W + (size_t)l * 128 * 128,
                                               cls_b + (size_t)l * 128, Hb, NN, 128, 128, 128);
  }

  col_mean<<<256, 128, 0, stream>>>(Hb, rep);
  head_kernel<<<1, 128, 0, stream>>>(rep, head_W, head_b, out);
}

// Round 3
// 961.267 us; speedup vs baseline: 1.3428x; 1.3428x over previous
//
#include <hip/hip_runtime.h>
#include <math.h>

#define NN 20000
#define EE 320000
#define NBINS 2048
#define HRANGE 64.0f
#define EPSF 1e-20f

typedef __attribute__((ext_vector_type(8))) short bf16x8;
typedef __attribute__((ext_vector_type(4))) float f32x4;

// ---------------- workspace layout (f32-slot offsets, all 16B-aligned) -----
// R2 bug: OFF_TB was sized NN*64 bf16 but agg128 writes tb 128-wide -> it
// clobbered Hb. tb is now sized NN*128 bf16 (used 64-wide by agg64, 128-wide
// by agg128).
constexpr size_t OFF_DEG  = 0;                    // NN ints
constexpr size_t OFF_RS   = 20000;                // NN+1 ints (+pad)
constexpr size_t OFF_CUR  = 40008;                // NN ints
constexpr size_t OFF_EIX  = 60008;                // EE ints
constexpr size_t OFF_GSRC = 380008;               // EE ints
constexpr size_t OFF_TB   = 700008;               // NN*128 bf16 (1280000 slots)
constexpr size_t OFF_HB   = 1980008;              // NN*128 bf16 (1280000)
constexpr size_t OFF_PA   = 3260008;              // NN*512 bf16 (5120000)
constexpr size_t OFF_PB   = 8380008;              // NN*512 bf16
constexpr size_t OFF_PE   = 13500008;             // EE f32
constexpr size_t OFF_DL   = 13820008;             // EE f32
constexpr size_t OFF_TT   = 14140008;             // EE f32
constexpr size_t OFF_HIST = 14460008;             // 2*NBINS f32
constexpr size_t OFF_SCAL = 14464104;             // 32 f32
constexpr size_t OFF_REP  = 14464136;             // 128 f32
constexpr size_t OFF_WT   = 14464264;             // 278528 bf16 (139264 slots)
// WT sub-offsets (bf16 units):
constexpr size_t WT_ENC0 = 0;         // 128x64
constexpr size_t WT_ENC  = 8192;      // 4 x 128x128
constexpr size_t WT_CLS0 = 73728;     // 128x64
constexpr size_t WT_CLS  = 81920;     // 4 x 128x128
constexpr size_t WT_EA1  = 147456;    // 512x256

__device__ __forceinline__ unsigned ordf(float f) {
  unsigned b = __float_as_uint(f);
  return (b >> 31) ? ~b : (b | 0x80000000u);
}
__device__ __forceinline__ float unordf(unsigned u) {
  unsigned b = (u >> 31) ? (u ^ 0x80000000u) : ~u;
  return __uint_as_float(b);
}
__device__ __forceinline__ ushort f2bf(float f) {   // RNE
  unsigned u = __float_as_uint(f);
  u += 0x7FFFu + ((u >> 16) & 1u);
  return (ushort)(u >> 16);
}
__device__ __forceinline__ float bf2f(ushort h) {
  return __uint_as_float(((unsigned)h) << 16);
}
__device__ __forceinline__ float bflo(unsigned v) { return __uint_as_float(v << 16); }
__device__ __forceinline__ float bfhi(unsigned v) { return __uint_as_float(v & 0xFFFF0000u); }

// ---------------- init ------------------------------------------------------
__global__ void init_ws(int* deg, int* cur, float* hist, float* scal, float* rep) {
  int i = blockIdx.x * blockDim.x + threadIdx.x;
  if (i < NN) { deg[i] = 0; cur[i] = 0; }
  if (i < 2 * NBINS) hist[i] = 0.f;
  if (i < 128) rep[i] = 0.f;
  if (i < 32) {
    if (i == 2)      ((unsigned*)scal)[2] = 0xFFFFFFFFu;
    else if (i == 3) ((unsigned*)scal)[3] = 0u;
    else scal[i] = 0.f;
  }
}

// ---------------- CSR build -------------------------------------------------
__global__ void count_deg(const int* __restrict__ dst, int* __restrict__ deg) {
  int e = blockIdx.x * 256 + threadIdx.x;
  if (e < EE) atomicAdd(&deg[dst[e]], 1);
}

__global__ void scan_deg(const int* __restrict__ deg, int* __restrict__ rs) {
  __shared__ int s[1024];
  __shared__ int carry;
  int tid = threadIdx.x;
  if (tid == 0) carry = 0;
  __syncthreads();
  for (int base = 0; base < NN; base += 1024) {
    int idx = base + tid;
    int v = (idx < NN) ? deg[idx] : 0;
    s[tid] = v;
    __syncthreads();
    for (int off = 1; off < 1024; off <<= 1) {
      int t = (tid >= off) ? s[tid - off] : 0;
      __syncthreads();
      s[tid] += t;
      __syncthreads();
    }
    if (idx < NN) rs[idx] = carry + s[tid] - v;
    __syncthreads();
    if (tid == 1023) carry += s[1023];
    __syncthreads();
  }
  if (tid == 0) rs[NN] = carry;
}

__global__ void fill_csr(const int* __restrict__ src, const int* __restrict__ dst,
                         const int* __restrict__ rs, int* __restrict__ cur,
                         int* __restrict__ eidx, int* __restrict__ gsrc) {
  int e = blockIdx.x * 256 + threadIdx.x;
  if (e < EE) {
    int d = dst[e];
    int p = atomicAdd(&cur[d], 1);
    int o = rs[d] + p;
    eidx[o] = e;
    gsrc[o] = src[e];
  }
}

// ---------------- weight transpose + bf16: dst[l][n][k] = src[l][k][n] ------
__global__ void transpose_w(const float* __restrict__ src, ushort* __restrict__ dst,
                            int K, int N, int total) {
  int i = blockIdx.x * 256 + threadIdx.x;
  if (i >= total) return;
  int kn = K * N;
  int l = i / kn;
  int rem = i - l * kn;
  int k = rem / N;
  int n = rem - k * N;
  dst[(size_t)l * kn + (size_t)n * K + k] = f2bf(src[i]);
}

// ---------------- GIN aggregation, C=64 (fp32 in, bf16 out) -----------------
__global__ __launch_bounds__(256) void agg64(
    const float* __restrict__ X, ushort* __restrict__ outb,
    const int* __restrict__ gsrc, const int* __restrict__ eidx,
    const int* __restrict__ rs, const float* __restrict__ att) {
  const int lane = threadIdx.x & 63;
  const int n = blockIdx.x * 4 + (threadIdx.x >> 6);
  if (n >= NN) return;
  const int e0 = rs[n], e1 = rs[n + 1];
  float a = X[(size_t)n * 64 + lane];
  for (int i = e0; i < e1; ++i) {
    float w = att ? att[eidx[i]] : 1.0f;
    a = fmaf(w, X[(size_t)gsrc[i] * 64 + lane], a);
  }
  outb[(size_t)n * 64 + lane] = f2bf(a);
}

// ---------------- GIN aggregation, C=128 (bf16 in/out) ----------------------
__global__ __launch_bounds__(256) void agg128(
    const ushort* __restrict__ Xb, ushort* __restrict__ outb,
    const int* __restrict__ gsrc, const int* __restrict__ eidx,
    const int* __restrict__ rs, const float* __restrict__ att) {
  const int lane = threadIdx.x & 63;
  const int n = blockIdx.x * 4 + (threadIdx.x >> 6);
  if (n >= NN) return;
  const int e0 = rs[n], e1 = rs[n + 1];
  const unsigned* X2 = (const unsigned*)Xb;
  unsigned self = X2[(size_t)n * 64 + lane];
  float ax = bflo(self), ay = bfhi(self);
  for (int i = e0; i < e1; ++i) {
    float w = att ? att[eidx[i]] : 1.0f;
    unsigned v = X2[(size_t)gsrc[i] * 64 + lane];
    ax = fmaf(w, bflo(v), ax);
    ay = fmaf(w, bfhi(v), ay);
  }
  unsigned o = (unsigned)f2bf(ax) | ((unsigned)f2bf(ay) << 16);
  ((unsigned*)outb)[(size_t)n * 64 + lane] = o;
}

// ---------------- MFMA GEMM: C(MxN bf16) = [relu](A(MxK bf16) @ B [+bias]) --
// A row-major (lda=K). Bt: pre-transposed weights, Bt[n][k], row stride ldbt.
// Block: 256 thr = 4 waves. Block tile 32(M) x 128(N). Wave: 16x64 (4 frags).
// M must be a multiple of 32 (20000 = 625*32).
template <bool BIAS, bool RELU>
__global__ __launch_bounds__(256) void gemm_mfma(
    const ushort* __restrict__ A, const ushort* __restrict__ Bt,
    const float* __restrict__ bias, ushort* __restrict__ C,
    int K, int ldbt, int ldc) {
  __shared__ float lds[32][132];
  const int tid = threadIdx.x;
  const int wave = tid >> 6;
  const int lane = tid & 63;
  const int quad = lane >> 4;
  const int l15 = lane & 15;
  const int mh = wave >> 1;
  const int nh = wave & 1;
  const int row0 = blockIdx.y * 32;
  const int col0 = blockIdx.x * 128;
  const int arow = row0 + mh * 16 + l15;
  f32x4 acc[4] = {{0.f, 0.f, 0.f, 0.f}, {0.f, 0.f, 0.f, 0.f},
                  {0.f, 0.f, 0.f, 0.f}, {0.f, 0.f, 0.f, 0.f}};
  const ushort* Ap = A + (size_t)arow * K + quad * 8;
  for (int k0 = 0; k0 < K; k0 += 32) {
    bf16x8 af = *(const bf16x8*)(Ap + k0);
#pragma unroll
    for (int t = 0; t < 4; ++t) {
      int bn = col0 + nh * 64 + t * 16 + l15;
      bf16x8 bf = *(const bf16x8*)(Bt + (size_t)bn * ldbt + k0 + quad * 8);
      acc[t] = __builtin_amdgcn_mfma_f32_16x16x32_bf16(af, bf, acc[t], 0, 0, 0);
    }
  }
#pragma unroll
  for (int t = 0; t < 4; ++t) {
    int lc = nh * 64 + t * 16 + l15;
    float bs = BIAS ? bias[col0 + lc] : 0.f;
#pragma unroll
    for (int r = 0; r < 4; ++r) {
      float v = acc[t][r] + bs;
      if (RELU) v = fmaxf(v, 0.f);
      lds[mh * 16 + quad * 4 + r][lc] = v;
    }
  }
  __syncthreads();
  const int r = tid >> 3;
  const int c0 = (tid & 7) * 16;
  ushort* Cp = C + (size_t)(row0 + r) * ldc + col0 + c0;
#pragma unroll
  for (int k = 0; k < 4; ++k) {
    f32x4 v = *(const f32x4*)&lds[r][c0 + k * 4];
    ushort4 o;
    o.x = f2bf(v[0]); o.y = f2bf(v[1]); o.z = f2bf(v[2]); o.w = f2bf(v[3]);
    *(ushort4*)(Cp + k * 4) = o;
  }
}

// ---------------- edge MLP second layer, CSR-by-dst, bf16 Pa/Pb -------------
// pe[e] = b2 + sum_j relu(Pa[src][j] + Pb[dst][j]) * W2[j]
__global__ __launch_bounds__(256) void edge_pe_csr(
    const ushort* __restrict__ Pa, const ushort* __restrict__ Pb,
    const int* __restrict__ gsrc, const int* __restrict__ eidx,
    const int* __restrict__ rs, const float* __restrict__ W2,
    const float* __restrict__ b2, float* __restrict__ pe) {
  const int lane = threadIdx.x & 63;
  const int n = blockIdx.x * 4 + (threadIdx.x >> 6);
  if (n >= NN) return;
  const int e0 = rs[n], e1 = rs[n + 1];
  if (e0 == e1) return;
  const float4* w2v = (const float4*)(W2 + lane * 8);
  float4 w0 = w2v[0], w1 = w2v[1];
  float w[8] = {w0.x, w0.y, w0.z, w0.w, w1.x, w1.y, w1.z, w1.w};
  uint4 pbv = *(const uint4*)(Pb + (size_t)n * 512 + lane * 8);
  float pb[8] = {bflo(pbv.x), bfhi(pbv.x), bflo(pbv.y), bfhi(pbv.y),
                 bflo(pbv.z), bfhi(pbv.z), bflo(pbv.w), bfhi(pbv.w)};
  const float b2v = b2[0];
  for (int i = e0; i < e1; ++i) {
    int e = eidx[i];
    int s = gsrc[i];
    uint4 pav = *(const uint4*)(Pa + (size_t)s * 512 + lane * 8);
    float pa[8] = {bflo(pav.x), bfhi(pav.x), bflo(pav.y), bfhi(pav.y),
                   bflo(pav.z), bfhi(pav.z), bflo(pav.w), bfhi(pav.w)};
    float acc = 0.f;
#pragma unroll
    for (int j = 0; j < 8; ++j) acc += fmaxf(pa[j] + pb[j], 0.f) * w[j];
#pragma unroll
    for (int off = 32; off; off >>= 1) acc += __shfl_xor(acc, off);
    if (lane == 0) pe[e] = acc + b2v;
  }
}

// ---------------- pe statistics (sum, sumsq, min, max) ----------------------
__global__ __launch_bounds__(256) void pe_stats(const float* __restrict__ pe,
                                                float* __restrict__ scal) {
  __shared__ float r1[256], r2[256], r3[256], r4[256];
  int tid = threadIdx.x;
  float s = 0.f, q = 0.f, mn = 3.0e38f, mx = -3.0e38f;
  for (int i = blockIdx.x * 256 + tid; i < EE; i += gridDim.x * 256) {
    float v = pe[i];
    s += v; q = fmaf(v, v, q);
    mn = fminf(mn, v); mx = fmaxf(mx, v);
  }
  r1[tid] = s; r2[tid] = q; r3[tid] = mn; r4[tid] = mx;
  __syncthreads();
  for (int k = 128; k > 0; k >>= 1) {
    if (tid < k) {
      r1[tid] += r1[tid + k];
      r2[tid] += r2[tid + k];
      r3[tid] = fminf(r3[tid], r3[tid + k]);
      r4[tid] = fmaxf(r4[tid], r4[tid + k]);
    }
    __syncthreads();
  }
  if (tid == 0) {
    unsafeAtomicAdd(&scal[0], r1[0]);
    unsafeAtomicAdd(&scal[1], r2[0]);
    atomicMin((unsigned*)scal + 2, ordf(r3[0]));
    atomicMax((unsigned*)scal + 3, ordf(r4[0]));
  }
}

// ---------------- delta + histogram -----------------------------------------
__global__ __launch_bounds__(256) void edge_delta_hist(
    const float* __restrict__ pe, const float* __restrict__ u,
    float* __restrict__ delta, float* __restrict__ hist,
    const float* __restrict__ scal) {
  __shared__ float cnt_s[NBINS], sum_s[NBINS];
  for (int b = threadIdx.x; b < NBINS; b += 256) { cnt_s[b] = 0.f; sum_s[b] = 0.f; }
  float sum = scal[0], ssq = scal[1];
  float mn = unordf(((const unsigned*)scal)[2]);
  float mx = unordf(((const unsigned*)scal)[3]);
  float mu = sum / (float)EE;
  float var = (ssq - sum * sum / (float)EE) / (float)(EE - 1);
  float istd = rsqrtf(fmaxf(var, 1e-30f));
  float shift = (mn - mu) * istd + (mx - mu) * istd;
  __syncthreads();
  for (int e = blockIdx.x * 256 + threadIdx.x; e < EE; e += gridDim.x * 256) {
    float atts = (pe[e] - mu) * istd;
    float g = -logf(-logf(u[e] + EPSF) + EPSF);
    float dl = 2.0f * (atts + g) - shift;
    delta[e] = dl;
    float dcl = fminf(fmaxf(dl, -HRANGE), HRANGE * 0.9999f);
    int b = (int)((dcl + HRANGE) * ((float)NBINS / (2.0f * HRANGE)));
    b = min(max(b, 0), NBINS - 1);
    atomicAdd(&cnt_s[b], 1.0f);
    atomicAdd(&sum_s[b], dcl);
  }
  __syncthreads();
  for (int b = threadIdx.x; b < NBINS; b += 256) {
    float c = cnt_s[b];
    if (c != 0.f) {
      unsafeAtomicAdd(&hist[b], c);
      unsafeAtomicAdd(&hist[NBINS + b], sum_s[b]);
    }
  }
}

// ---------------- scalar Sinkhorn recursion ---------------------------------
__global__ __launch_bounds__(256) void sinkhorn_iter(const float* __restrict__ hist,
                                                     float* __restrict__ scal) {
  __shared__ float red[256];
  int tid = threadIdx.x;
  float cnt[NBINS / 256], mean[NBINS / 256];
#pragma unroll
  for (int i = 0; i < NBINS / 256; i++) {
    int b = tid + i * 256;
    float c = hist[b];
    cnt[i] = c;
    mean[i] = (c > 0.f) ? hist[NBINS + b] / c : 0.f;
  }
  const float LRD = -1.0986122886681098f;
  float S = 0.f, Zfin = 0.f;
  for (int it = 0; it < 30; ++it) {
    float p = 0.f;
#pragma unroll
    for (int i = 0; i < NBINS / 256; i++)
      if (cnt[i] > 0.f) p += cnt[i] / (1.f + expf(-(mean[i] + S)));
    red[tid] = p;
    __syncthreads();
    for (int k = 128; k > 0; k >>= 1) {
      if (tid < k) red[tid] += red[tid + k];
      __syncthreads();
    }
    float Z = red[0];
    __syncthreads();
    if (it < 29)
      S += logf(fmaxf((float)EE - Z, 1.0f)) - logf(Z) + LRD;
    else
      Zfin = Z;
  }
  if (tid == 0) {
    scal[8] = S;
    scal[9] = ((float)EE * 0.25f) / Zfin;
  }
}

// ---------------- T_e -------------------------------------------------------
__global__ void compute_T(const float* __restrict__ delta,
                          const float* __restrict__ scal,
                          float* __restrict__ Ta) {
  int i = blockIdx.x * 256 + threadIdx.x;
  if (i >= EE) return;
  float S = scal[8], sc = scal[9];
  Ta[i] = sc / (1.f + expf(-(delta[i] + S)));
}

// ---------------- mean pooling + head ---------------------------------------
__global__ __launch_bounds__(128) void col_mean(const ushort* __restrict__ Hc,
                                                float* __restrict__ rep) {
  int c = threadIdx.x;
  float p = 0.f;
  for (int n = blockIdx.x; n < NN; n += gridDim.x) p += bf2f(Hc[(size_t)n * 128 + c]);
  unsafeAtomicAdd(&rep[c], p);
}

__global__ __launch_bounds__(128) void head_kernel(const float* __restrict__ repsum,
                                                   const float* __restrict__ hW,
                                                   const float* __restrict__ hb,
                                                   float* __restrict__ out) {
  __shared__ float rep[128];
  int tid = threadIdx.x;
  if (tid < 128) rep[tid] = repsum[tid] * (1.0f / (float)NN);
  __syncthreads();
  if (tid < 10) {
    float a = hb[tid];
#pragma unroll
    for (int c = 0; c < 128; c++) a = fmaf(rep[c], hW[c * 10 + tid], a);
    out[tid] = a;
  }
}

// ---------------- launch ----------------------------------------------------
extern "C" void kernel_launch(void* const* d_in, const int* in_sizes, int n_in,
                              void* d_out, int out_size, void* d_ws, size_t ws_size,
                              hipStream_t stream) {
  const float* x      = (const float*)d_in[0];
  const int*   ei     = (const int*)d_in[1];
  const float* u      = (const float*)d_in[2];
  const float* enc_W0 = (const float*)d_in[3];
  const float* enc_b0 = (const float*)d_in[4];
  const float* enc_W  = (const float*)d_in[5];
  const float* enc_b  = (const float*)d_in[6];
  const float* ea_W1  = (const float*)d_in[7];
  const float* ea_b1  = (const float*)d_in[8];
  const float* ea_W2  = (const float*)d_in[9];
  const float* ea_b2  = (const float*)d_in[10];
  const float* cls_W0 = (const float*)d_in[11];
  const float* cls_b0 = (const float*)d_in[12];
  const float* cls_W  = (const float*)d_in[13];
  const float* cls_b  = (const float*)d_in[14];
  const float* head_W = (const float*)d_in[15];
  const float* head_b = (const float*)d_in[16];
  const int* src  = ei;
  const int* dstp = ei + EE;

  float* wsF = (float*)d_ws;
  int*   wsI = (int*)d_ws;
  int* deg  = wsI + OFF_DEG;
  int* rs   = wsI + OFF_RS;
  int* cur  = wsI + OFF_CUR;
  int* eix  = wsI + OFF_EIX;
  int* gsrc = wsI + OFF_GSRC;
  ushort* tb = (ushort*)(wsF + OFF_TB);
  ushort* Hb = (ushort*)(wsF + OFF_HB);
  ushort* Pa = (ushort*)(wsF + OFF_PA);
  ushort* Pb = (ushort*)(wsF + OFF_PB);
  float* pe   = wsF + OFF_PE;
  float* dl   = wsF + OFF_DL;
  float* Ta   = wsF + OFF_TT;
  float* hist = wsF + OFF_HIST;
  float* scal = wsF + OFF_SCAL;
  float* rep  = wsF + OFF_REP;
  ushort* Wt  = (ushort*)(wsF + OFF_WT);
  ushort* W0et = Wt + WT_ENC0;
  ushort* Wet  = Wt + WT_ENC;
  ushort* W0ct = Wt + WT_CLS0;
  ushort* Wct  = Wt + WT_CLS;
  ushort* W1t  = Wt + WT_EA1;
  float* out = (float*)d_out;

  init_ws<<<(NN + 255) / 256, 256, 0, stream>>>(deg, cur, hist, scal, rep);
  count_deg<<<(EE + 255) / 256, 256, 0, stream>>>(dstp, deg);
  scan_deg<<<1, 1024, 0, stream>>>(deg, rs);
  fill_csr<<<(EE + 255) / 256, 256, 0, stream>>>(src, dstp, rs, cur, eix, gsrc);

  // weight transposes → bf16
  transpose_w<<<(64 * 128 + 255) / 256, 256, 0, stream>>>(enc_W0, W0et, 64, 128, 64 * 128);
  transpose_w<<<(4 * 128 * 128 + 255) / 256, 256, 0, stream>>>(enc_W, Wet, 128, 128, 4 * 128 * 128);
  transpose_w<<<(64 * 128 + 255) / 256, 256, 0, stream>>>(cls_W0, W0ct, 64, 128, 64 * 128);
  transpose_w<<<(4 * 128 * 128 + 255) / 256, 256, 0, stream>>>(cls_W, Wct, 128, 128, 4 * 128 * 128);
  transpose_w<<<(256 * 512 + 255) / 256, 256, 0, stream>>>(ea_W1, W1t, 256, 512, 256 * 512);

  dim3 gN1(1, NN / 32);   // N=128
  dim3 gN4(4, NN / 32);   // N=512

  // encoder GIN stack (att = 1)
  agg64<<<(NN + 3) / 4, 256, 0, stream>>>(x, tb, gsrc, eix, rs, nullptr);
  gemm_mfma<true, true><<<gN1, 256, 0, stream>>>(tb, W0et, enc_b0, Hb, 64, 64, 128);
  for (int l = 0; l < 4; l++) {
    agg128<<<(NN + 3) / 4, 256, 0, stream>>>(Hb, tb, gsrc, eix, rs, nullptr);
    gemm_mfma<true, true><<<gN1, 256, 0, stream>>>(tb, Wet + (size_t)l * 128 * 128,
                                                   enc_b + (size_t)l * 128, Hb, 128, 128, 128);
  }

  // edge MLP factorized: Pa = H@W1a + b1 (bf16), Pb = H@W1b (bf16)
  gemm_mfma<true, false><<<gN4, 256, 0, stream>>>(Hb, W1t, ea_b1, Pa, 128, 256, 512);
  gemm_mfma<false, false><<<gN4, 256, 0, stream>>>(Hb, W1t + 128, nullptr, Pb, 128, 256, 512);
  edge_pe_csr<<<(NN + 3) / 4, 256, 0, stream>>>(Pa, Pb, gsrc, eix, rs, ea_W2, ea_b2, pe);

  // standardize + gumbel + delta + histogram → scalar Sinkhorn → T
  pe_stats<<<512, 256, 0, stream>>>(pe, scal);
  edge_delta_hist<<<128, 256, 0, stream>>>(pe, u, dl, hist, scal);
  sinkhorn_iter<<<1, 256, 0, stream>>>(hist, scal);
  compute_T<<<(EE + 255) / 256, 256, 0, stream>>>(dl, scal, Ta);

  // classifier GIN stack (att = T)
  agg64<<<(NN + 3) / 4, 256, 0, stream>>>(x, tb, gsrc, eix, rs, Ta);
  gemm_mfma<true, true><<<gN1, 256, 0, stream>>>(tb, W0ct, cls_b0, Hb, 64, 64, 128);
  for (int l = 0; l < 4; l++) {
    agg128<<<(NN + 3) / 4, 256, 0, stream>>>(Hb, tb, gsrc, eix, rs, Ta);
    gemm_mfma<true, true><<<gN1, 256, 0, stream>>>(tb, Wct + (size_t)l * 128 * 128,
                                                   cls_b + (size_t)l * 128, Hb, 128, 128, 128);
  }

  col_mean<<<256, 128, 0, stream>>>(Hb, rep);
  head_kernel<<<1, 128, 0, stream>>>(rep, head_W, head_b, out);
}

// Round 4
// 748.957 us; speedup vs baseline: 1.7235x; 1.2835x over previous
//
#include <hip/hip_runtime.h>
#include <math.h>

#define NN 20000
#define EE 320000
#define NBINS 2048
#define HRANGE 64.0f
#define EPSF 1e-20f

typedef __attribute__((ext_vector_type(8))) short bf16x8;
typedef __attribute__((ext_vector_type(4))) float f32x4;

// ---------------- workspace layout (f32-slot offsets, all 16B-aligned) -----
constexpr size_t OFF_DEG  = 0;                    // NN ints
constexpr size_t OFF_RS   = 20000;                // NN+1 ints (+pad)
constexpr size_t OFF_CUR  = 40008;                // NN ints
constexpr size_t OFF_EIX  = 60008;                // EE ints
constexpr size_t OFF_GSRC = 380008;               // EE ints
constexpr size_t OFF_B0   = 700008;               // NN*128 bf16 (1280000 slots)
constexpr size_t OFF_B1   = 1980008;              // NN*128 bf16
constexpr size_t OFF_PA   = 3260008;              // NN*512 bf16
constexpr size_t OFF_PB   = 8380008;              // NN*512 bf16
constexpr size_t OFF_PE   = 13500008;             // EE f32 (CSR order)
constexpr size_t OFF_DL   = 13820008;             // EE f32 (CSR order)
constexpr size_t OFF_TT   = 14140008;             // EE f32 (CSR order)
constexpr size_t OFF_HIST = 14460008;             // 2*NBINS f32
constexpr size_t OFF_SCAL = 14464104;             // 32 f32
constexpr size_t OFF_REP  = 14464136;             // 128 f32
constexpr size_t OFF_WT   = 14464264;             // 278528 bf16
// WT sub-offsets (bf16 units):
constexpr size_t WT_ENC0 = 0;         // 128x64 (n-major)
constexpr size_t WT_ENC  = 8192;      // 4 x 128x128
constexpr size_t WT_CLS0 = 73728;     // 128x64
constexpr size_t WT_CLS  = 81920;     // 4 x 128x128
constexpr size_t WT_EA1  = 147456;    // 512x256

__device__ __forceinline__ unsigned ordf(float f) {
  unsigned b = __float_as_uint(f);
  return (b >> 31) ? ~b : (b | 0x80000000u);
}
__device__ __forceinline__ float unordf(unsigned u) {
  unsigned b = (u >> 31) ? (u ^ 0x80000000u) : ~u;
  return __uint_as_float(b);
}
__device__ __forceinline__ ushort f2bf(float f) {   // RNE
  unsigned u = __float_as_uint(f);
  u += 0x7FFFu + ((u >> 16) & 1u);
  return (ushort)(u >> 16);
}
__device__ __forceinline__ unsigned pack2(float x, float y) {
  return (unsigned)f2bf(x) | ((unsigned)f2bf(y) << 16);
}
__device__ __forceinline__ float bf2f(ushort h) {
  return __uint_as_float(((unsigned)h) << 16);
}
__device__ __forceinline__ float bflo(unsigned v) { return __uint_as_float(v << 16); }
__device__ __forceinline__ float bfhi(unsigned v) { return __uint_as_float(v & 0xFFFF0000u); }

// ---------------- init ------------------------------------------------------
__global__ void init_ws(int* deg, int* cur, float* hist, float* scal, float* rep) {
  int i = blockIdx.x * blockDim.x + threadIdx.x;
  if (i < NN) { deg[i] = 0; cur[i] = 0; }
  if (i < 2 * NBINS) hist[i] = 0.f;
  if (i < 128) rep[i] = 0.f;
  if (i < 32) {
    if (i == 2)      ((unsigned*)scal)[2] = 0xFFFFFFFFu;
    else if (i == 3) ((unsigned*)scal)[3] = 0u;
    else scal[i] = 0.f;
  }
}

// ---------------- CSR build -------------------------------------------------
__global__ void count_deg(const int* __restrict__ dst, int* __restrict__ deg) {
  int e = blockIdx.x * 256 + threadIdx.x;
  if (e < EE) atomicAdd(&deg[dst[e]], 1);
}

// thread-sequential chunks + one block scan (2 barrier phases, not 400)
__global__ __launch_bounds__(1024) void scan_deg(const int* __restrict__ deg,
                                                 int* __restrict__ rs) {
  __shared__ int ps[1024];
  const int t = threadIdx.x;
  const int base = t * 20;
  int loc[20];
  int s = 0;
#pragma unroll
  for (int j = 0; j < 20; ++j) {
    int idx = base + j;
    int v = (idx < NN) ? deg[idx] : 0;
    loc[j] = s;
    s += v;
  }
  ps[t] = s;
  __syncthreads();
  for (int off = 1; off < 1024; off <<= 1) {
    int x = (t >= off) ? ps[t - off] : 0;
    __syncthreads();
    ps[t] += x;
    __syncthreads();
  }
  const int excl = ps[t] - s;
#pragma unroll
  for (int j = 0; j < 20; ++j) {
    int idx = base + j;
    if (idx < NN) rs[idx] = excl + loc[j];
  }
  if (t == 1023) rs[NN] = ps[1023];
}

__global__ void fill_csr(const int* __restrict__ src, const int* __restrict__ dst,
                         const int* __restrict__ rs, int* __restrict__ cur,
                         int* __restrict__ eidx, int* __restrict__ gsrc) {
  int e = blockIdx.x * 256 + threadIdx.x;
  if (e < EE) {
    int d = dst[e];
    int p = atomicAdd(&cur[d], 1);
    int o = rs[d] + p;
    eidx[o] = e;
    gsrc[o] = src[e];
  }
}

// ---------------- all weight transposes in one kernel -----------------------
__global__ void transpose_all(const float* __restrict__ encW0, const float* __restrict__ encW,
                              const float* __restrict__ clsW0, const float* __restrict__ clsW,
                              const float* __restrict__ eaW1, ushort* __restrict__ Wt) {
  int i = blockIdx.x * 256 + threadIdx.x;
  if (i < 8192) {                       // enc_W0: 64x128 -> [n][k]
    int k = i >> 7, n = i & 127;
    Wt[WT_ENC0 + n * 64 + k] = f2bf(encW0[i]);
  } else if (i < 73728) {               // enc_W: 4 x 128x128
    int j = i - 8192;
    int l = j >> 14, r = j & 16383, k = r >> 7, n = r & 127;
    Wt[WT_ENC + l * 16384 + n * 128 + k] = f2bf(encW[j]);
  } else if (i < 81920) {               // cls_W0
    int j = i - 73728;
    int k = j >> 7, n = j & 127;
    Wt[WT_CLS0 + n * 64 + k] = f2bf(clsW0[j]);
  } else if (i < 147456) {              // cls_W
    int j = i - 81920;
    int l = j >> 14, r = j & 16383, k = r >> 7, n = r & 127;
    Wt[WT_CLS + l * 16384 + n * 128 + k] = f2bf(clsW[j]);
  } else if (i < 278528) {              // ea_W1: 256x512 -> [n][k]
    int j = i - 147456;
    int k = j >> 9, n = j & 511;
    Wt[WT_EA1 + n * 256 + k] = f2bf(eaW1[j]);
  }
}

// ---------------- fused GIN layer, K=64 (fp32 x in, bf16 out) ---------------
// Block: 256 thr, 32 nodes. Phase 1: 16-lane groups gather-aggregate into LDS
// (bf16, padded stride). Phase 2: MFMA 32x128 tile. C = relu((x+agg)@W + b).
template <bool HASATT>
__global__ __launch_bounds__(256) void fused_layer64(
    const float* __restrict__ X, ushort* __restrict__ C,
    const int* __restrict__ gsrc, const int* __restrict__ rs,
    const float* __restrict__ att, const ushort* __restrict__ Bt,
    const float* __restrict__ bias) {
  __shared__ __align__(16) char smem[16896];
  ushort* Asm = (ushort*)smem;                 // [32][72] stride 72 bf16
  const int tid = threadIdx.x;
  const int g = tid >> 4, l = tid & 15;
  const int nb = blockIdx.x * 32;
#pragma unroll
  for (int half = 0; half < 2; ++half) {
    const int nl = g + half * 16;
    const int n = nb + nl;
    const int e0 = rs[n], e1 = rs[n + 1];
    float4 a = ((const float4*)(X + (size_t)n * 64))[l];
    int i = e0;
    float4 v;
    float w = 1.f;
    if (i < e1) {
      int s = gsrc[i];
      if (HASATT) w = att[i];
      v = ((const float4*)(X + (size_t)s * 64))[l];
    }
    while (i < e1) {
      int i2 = i + 1;
      float4 v2;
      float wn = 1.f;
      if (i2 < e1) {
        int s2 = gsrc[i2];
        if (HASATT) wn = att[i2];
        v2 = ((const float4*)(X + (size_t)s2 * 64))[l];
      }
      a.x = fmaf(w, v.x, a.x); a.y = fmaf(w, v.y, a.y);
      a.z = fmaf(w, v.z, a.z); a.w = fmaf(w, v.w, a.w);
      v = v2; w = wn; i = i2;
    }
    uint2 o;
    o.x = pack2(a.x, a.y);
    o.y = pack2(a.z, a.w);
    *(uint2*)(Asm + nl * 72 + l * 4) = o;
  }
  __syncthreads();
  const int wave = tid >> 6, lane = tid & 63, quad = lane >> 4, l15 = lane & 15;
  const int mh = wave >> 1, nh = wave & 1;
  f32x4 acc[4] = {{0.f, 0.f, 0.f, 0.f}, {0.f, 0.f, 0.f, 0.f},
                  {0.f, 0.f, 0.f, 0.f}, {0.f, 0.f, 0.f, 0.f}};
#pragma unroll
  for (int k0 = 0; k0 < 64; k0 += 32) {
    bf16x8 af = *(const bf16x8*)(Asm + (mh * 16 + l15) * 72 + k0 + quad * 8);
#pragma unroll
    for (int t = 0; t < 4; ++t) {
      int bn = nh * 64 + t * 16 + l15;
      bf16x8 bf = *(const bf16x8*)(Bt + (size_t)bn * 64 + k0 + quad * 8);
      acc[t] = __builtin_amdgcn_mfma_f32_16x16x32_bf16(af, bf, acc[t], 0, 0, 0);
    }
  }
  __syncthreads();
  float (*Csm)[132] = (float(*)[132])smem;
#pragma unroll
  for (int t = 0; t < 4; ++t) {
    int lc = nh * 64 + t * 16 + l15;
    float bs = bias[lc];
#pragma unroll
    for (int r = 0; r < 4; ++r)
      Csm[mh * 16 + quad * 4 + r][lc] = fmaxf(acc[t][r] + bs, 0.f);
  }
  __syncthreads();
  const int r = tid >> 3, c0 = (tid & 7) * 16;
  ushort* Cp = C + (size_t)(nb + r) * 128 + c0;
#pragma unroll
  for (int k = 0; k < 4; ++k) {
    f32x4 vv = *(const f32x4*)&Csm[r][c0 + k * 4];
    ushort4 o;
    o.x = f2bf(vv[0]); o.y = f2bf(vv[1]); o.z = f2bf(vv[2]); o.w = f2bf(vv[3]);
    *(ushort4*)(Cp + k * 4) = o;
  }
}

// ---------------- fused GIN layer, K=128 (bf16 in/out) ----------------------
template <bool HASATT>
__global__ __launch_bounds__(256) void fused_layer128(
    const ushort* __restrict__ Xb, ushort* __restrict__ C,
    const int* __restrict__ gsrc, const int* __restrict__ rs,
    const float* __restrict__ att, const ushort* __restrict__ Bt,
    const float* __restrict__ bias) {
  __shared__ __align__(16) char smem[16896];
  ushort* Asm = (ushort*)smem;                 // [32][136] stride 136 bf16
  const int tid = threadIdx.x;
  const int g = tid >> 4, l = tid & 15;
  const int nb = blockIdx.x * 32;
#pragma unroll
  for (int half = 0; half < 2; ++half) {
    const int nl = g + half * 16;
    const int n = nb + nl;
    const int e0 = rs[n], e1 = rs[n + 1];
    float a[8];
    {
      uint4 sv = ((const uint4*)(Xb + (size_t)n * 128))[l];
      a[0] = bflo(sv.x); a[1] = bfhi(sv.x); a[2] = bflo(sv.y); a[3] = bfhi(sv.y);
      a[4] = bflo(sv.z); a[5] = bfhi(sv.z); a[6] = bflo(sv.w); a[7] = bfhi(sv.w);
    }
    int i = e0;
    uint4 v;
    float w = 1.f;
    if (i < e1) {
      int s = gsrc[i];
      if (HASATT) w = att[i];
      v = ((const uint4*)(Xb + (size_t)s * 128))[l];
    }
    while (i < e1) {
      int i2 = i + 1;
      uint4 v2;
      float wn = 1.f;
      if (i2 < e1) {
        int s2 = gsrc[i2];
        if (HASATT) wn = att[i2];
        v2 = ((const uint4*)(Xb + (size_t)s2 * 128))[l];
      }
      a[0] = fmaf(w, bflo(v.x), a[0]); a[1] = fmaf(w, bfhi(v.x), a[1]);
      a[2] = fmaf(w, bflo(v.y), a[2]); a[3] = fmaf(w, bfhi(v.y), a[3]);
      a[4] = fmaf(w, bflo(v.z), a[4]); a[5] = fmaf(w, bfhi(v.z), a[5]);
      a[6] = fmaf(w, bflo(v.w), a[6]); a[7] = fmaf(w, bfhi(v.w), a[7]);
      v = v2; w = wn; i = i2;
    }
    uint4 o;
    o.x = pack2(a[0], a[1]); o.y = pack2(a[2], a[3]);
    o.z = pack2(a[4], a[5]); o.w = pack2(a[6], a[7]);
    *(uint4*)(Asm + nl * 136 + l * 8) = o;
  }
  __syncthreads();
  const int wave = tid >> 6, lane = tid & 63, quad = lane >> 4, l15 = lane & 15;
  const int mh = wave >> 1, nh = wave & 1;
  f32x4 acc[4] = {{0.f, 0.f, 0.f, 0.f}, {0.f, 0.f, 0.f, 0.f},
                  {0.f, 0.f, 0.f, 0.f}, {0.f, 0.f, 0.f, 0.f}};
#pragma unroll
  for (int k0 = 0; k0 < 128; k0 += 32) {
    bf16x8 af = *(const bf16x8*)(Asm + (mh * 16 + l15) * 136 + k0 + quad * 8);
#pragma unroll
    for (int t = 0; t < 4; ++t) {
      int bn = nh * 64 + t * 16 + l15;
      bf16x8 bf = *(const bf16x8*)(Bt + (size_t)bn * 128 + k0 + quad * 8);
      acc[t] = __builtin_amdgcn_mfma_f32_16x16x32_bf16(af, bf, acc[t], 0, 0, 0);
    }
  }
  __syncthreads();
  float (*Csm)[132] = (float(*)[132])smem;
#pragma unroll
  for (int t = 0; t < 4; ++t) {
    int lc = nh * 64 + t * 16 + l15;
    float bs = bias[lc];
#pragma unroll
    for (int r = 0; r < 4; ++r)
      Csm[mh * 16 + quad * 4 + r][lc] = fmaxf(acc[t][r] + bs, 0.f);
  }
  __syncthreads();
  const int r = tid >> 3, c0 = (tid & 7) * 16;
  ushort* Cp = C + (size_t)(nb + r) * 128 + c0;
#pragma unroll
  for (int k = 0; k < 4; ++k) {
    f32x4 vv = *(const f32x4*)&Csm[r][c0 + k * 4];
    ushort4 o;
    o.x = f2bf(vv[0]); o.y = f2bf(vv[1]); o.z = f2bf(vv[2]); o.w = f2bf(vv[3]);
    *(ushort4*)(Cp + k * 4) = o;
  }
}

// ---------------- Pa/Pb in one launch: grid (8, 625) ------------------------
// bx<4: Pa tile (bias), bx>=4: Pb tile. A=Hb direct from global.
__global__ __launch_bounds__(256) void gemm_papb(
    const ushort* __restrict__ Hb, const ushort* __restrict__ W1t,
    const float* __restrict__ b1, ushort* __restrict__ Pa, ushort* __restrict__ Pb) {
  __shared__ float lds[32][132];
  const int tid = threadIdx.x;
  const int wave = tid >> 6, lane = tid & 63, quad = lane >> 4, l15 = lane & 15;
  const int mh = wave >> 1, nh = wave & 1;
  const bool isB = blockIdx.x >= 4;
  const int col0 = (blockIdx.x & 3) * 128;
  const int row0 = blockIdx.y * 32;
  const ushort* Bt = W1t + (isB ? 128 : 0);
  ushort* C = isB ? Pb : Pa;
  f32x4 acc[4] = {{0.f, 0.f, 0.f, 0.f}, {0.f, 0.f, 0.f, 0.f},
                  {0.f, 0.f, 0.f, 0.f}, {0.f, 0.f, 0.f, 0.f}};
  const ushort* Ap = Hb + (size_t)(row0 + mh * 16 + l15) * 128 + quad * 8;
#pragma unroll
  for (int k0 = 0; k0 < 128; k0 += 32) {
    bf16x8 af = *(const bf16x8*)(Ap + k0);
#pragma unroll
    for (int t = 0; t < 4; ++t) {
      int bn = col0 + nh * 64 + t * 16 + l15;
      bf16x8 bf = *(const bf16x8*)(Bt + (size_t)bn * 256 + k0 + quad * 8);
      acc[t] = __builtin_amdgcn_mfma_f32_16x16x32_bf16(af, bf, acc[t], 0, 0, 0);
    }
  }
#pragma unroll
  for (int t = 0; t < 4; ++t) {
    int lc = nh * 64 + t * 16 + l15;
    float bs = isB ? 0.f : b1[col0 + lc];
#pragma unroll
    for (int r = 0; r < 4; ++r)
      lds[mh * 16 + quad * 4 + r][lc] = acc[t][r] + bs;
  }
  __syncthreads();
  const int r = tid >> 3, c0 = (tid & 7) * 16;
  ushort* Cp = C + (size_t)(row0 + r) * 512 + col0 + c0;
#pragma unroll
  for (int k = 0; k < 4; ++k) {
    f32x4 v = *(const f32x4*)&lds[r][c0 + k * 4];
    ushort4 o;
    o.x = f2bf(v[0]); o.y = f2bf(v[1]); o.z = f2bf(v[2]); o.w = f2bf(v[3]);
    *(ushort4*)(Cp + k * 4) = o;
  }
}

// ---------------- edge MLP layer 2, CSR order out, depth-2 prefetch ---------
__global__ __launch_bounds__(256) void edge_pe_csr(
    const ushort* __restrict__ Pa, const ushort* __restrict__ Pb,
    const int* __restrict__ gsrc, const int* __restrict__ rs,
    const float* __restrict__ W2, const float* __restrict__ b2,
    float* __restrict__ pe) {
  const int lane = threadIdx.x & 63;
  const int n = blockIdx.x * 4 + (threadIdx.x >> 6);
  if (n >= NN) return;
  const int e0 = rs[n], e1 = rs[n + 1];
  if (e0 == e1) return;
  const float4* w2v = (const float4*)(W2 + lane * 8);
  float4 w0 = w2v[0], w1 = w2v[1];
  float w[8] = {w0.x, w0.y, w0.z, w0.w, w1.x, w1.y, w1.z, w1.w};
  uint4 pbv = *(const uint4*)(Pb + (size_t)n * 512 + lane * 8);
  float pb[8] = {bflo(pbv.x), bfhi(pbv.x), bflo(pbv.y), bfhi(pbv.y),
                 bflo(pbv.z), bfhi(pbv.z), bflo(pbv.w), bfhi(pbv.w)};
  const float b2v = b2[0];
  int i = e0;
  uint4 pav = *(const uint4*)(Pa + (size_t)gsrc[i] * 512 + lane * 8);
  while (i < e1) {
    int i2 = i + 1;
    uint4 pav2;
    if (i2 < e1) pav2 = *(const uint4*)(Pa + (size_t)gsrc[i2] * 512 + lane * 8);
    float pa[8] = {bflo(pav.x), bfhi(pav.x), bflo(pav.y), bfhi(pav.y),
                   bflo(pav.z), bfhi(pav.z), bflo(pav.w), bfhi(pav.w)};
    float acc = 0.f;
#pragma unroll
    for (int j = 0; j < 8; ++j) acc += fmaxf(pa[j] + pb[j], 0.f) * w[j];
#pragma unroll
    for (int off = 32; off; off >>= 1) acc += __shfl_xor(acc, off);
    if (lane == 0) pe[i] = acc + b2v;
    pav = pav2;
    i = i2;
  }
}

// ---------------- pe statistics (sum, sumsq, min, max) ----------------------
__global__ __launch_bounds__(256) void pe_stats(const float* __restrict__ pe,
                                                float* __restrict__ scal) {
  __shared__ float r1[256], r2[256], r3[256], r4[256];
  int tid = threadIdx.x;
  float s = 0.f, q = 0.f, mn = 3.0e38f, mx = -3.0e38f;
  for (int i = blockIdx.x * 256 + tid; i < EE; i += gridDim.x * 256) {
    float v = pe[i];
    s += v; q = fmaf(v, v, q);
    mn = fminf(mn, v); mx = fmaxf(mx, v);
  }
  r1[tid] = s; r2[tid] = q; r3[tid] = mn; r4[tid] = mx;
  __syncthreads();
  for (int k = 128; k > 0; k >>= 1) {
    if (tid < k) {
      r1[tid] += r1[tid + k];
      r2[tid] += r2[tid + k];
      r3[tid] = fminf(r3[tid], r3[tid + k]);
      r4[tid] = fmaxf(r4[tid], r4[tid + k]);
    }
    __syncthreads();
  }
  if (tid == 0) {
    unsafeAtomicAdd(&scal[0], r1[0]);
    unsafeAtomicAdd(&scal[1], r2[0]);
    atomicMin((unsigned*)scal + 2, ordf(r3[0]));
    atomicMax((unsigned*)scal + 3, ordf(r4[0]));
  }
}

// ---------------- delta + histogram (CSR order; u gathered via eidx) --------
__global__ __launch_bounds__(256) void edge_delta_hist(
    const float* __restrict__ pe, const float* __restrict__ u,
    const int* __restrict__ eidx, float* __restrict__ delta,
    float* __restrict__ hist, const float* __restrict__ scal) {
  __shared__ float cnt_s[NBINS], sum_s[NBINS];
  for (int b = threadIdx.x; b < NBINS; b += 256) { cnt_s[b] = 0.f; sum_s[b] = 0.f; }
  float sum = scal[0], ssq = scal[1];
  float mn = unordf(((const unsigned*)scal)[2]);
  float mx = unordf(((const unsigned*)scal)[3]);
  float mu = sum / (float)EE;
  float var = (ssq - sum * sum / (float)EE) / (float)(EE - 1);
  float istd = rsqrtf(fmaxf(var, 1e-30f));
  float shift = (mn - mu) * istd + (mx - mu) * istd;
  __syncthreads();
  for (int i = blockIdx.x * 256 + threadIdx.x; i < EE; i += gridDim.x * 256) {
    float uu = u[eidx[i]];
    float atts = (pe[i] - mu) * istd;
    float g = -logf(-logf(uu + EPSF) + EPSF);
    float dl = 2.0f * (atts + g) - shift;
    delta[i] = dl;
    float dcl = fminf(fmaxf(dl, -HRANGE), HRANGE * 0.9999f);
    int b = (int)((dcl + HRANGE) * ((float)NBINS / (2.0f * HRANGE)));
    b = min(max(b, 0), NBINS - 1);
    atomicAdd(&cnt_s[b], 1.0f);
    atomicAdd(&sum_s[b], dcl);
  }
  __syncthreads();
  for (int b = threadIdx.x; b < NBINS; b += 256) {
    float c = cnt_s[b];
    if (c != 0.f) {
      unsafeAtomicAdd(&hist[b], c);
      unsafeAtomicAdd(&hist[NBINS + b], sum_s[b]);
    }
  }
}

// ---------------- scalar Sinkhorn recursion (single wave, no barriers) ------
__global__ __launch_bounds__(64) void sinkhorn_iter(const float* __restrict__ hist,
                                                    float* __restrict__ scal) {
  const int lane = threadIdx.x;
  float cnt[32], mean[32];
#pragma unroll
  for (int b = 0; b < 32; ++b) {
    int idx = b * 64 + lane;
    float c = hist[idx];
    cnt[b] = c;
    mean[b] = (c > 0.f) ? hist[NBINS + idx] / c : 0.f;
  }
  const float LRD = -1.0986122886681098f;
  float S = 0.f, Zfin = 0.f;
  for (int it = 0; it < 30; ++it) {
    float p = 0.f;
#pragma unroll
    for (int b = 0; b < 32; ++b)
      if (cnt[b] > 0.f) p += cnt[b] / (1.f + expf(-(mean[b] + S)));
#pragma unroll
    for (int off = 32; off; off >>= 1) p += __shfl_xor(p, off);
    if (it < 29)
      S += logf(fmaxf((float)EE - p, 1.0f)) - logf(p) + LRD;
    else
      Zfin = p;
  }
  if (lane == 0) {
    scal[8] = S;
    scal[9] = ((float)EE * 0.25f) / Zfin;
  }
}

// ---------------- T_i (CSR order) -------------------------------------------
__global__ void compute_T(const float* __restrict__ delta,
                          const float* __restrict__ scal,
                          float* __restrict__ Ta) {
  int i = blockIdx.x * 256 + threadIdx.x;
  if (i >= EE) return;
  float S = scal[8], sc = scal[9];
  Ta[i] = sc / (1.f + expf(-(delta[i] + S)));
}

// ---------------- mean pooling + head ---------------------------------------
__global__ __launch_bounds__(128) void col_mean(const ushort* __restrict__ Hc,
                                                float* __restrict__ rep) {
  int c = threadIdx.x;
  float p = 0.f;
  for (int n = blockIdx.x; n < NN; n += gridDim.x) p += bf2f(Hc[(size_t)n * 128 + c]);
  unsafeAtomicAdd(&rep[c], p);
}

__global__ __launch_bounds__(128) void head_kernel(const float* __restrict__ repsum,
                                                   const float* __restrict__ hW,
                                                   const float* __restrict__ hb,
                                                   float* __restrict__ out) {
  __shared__ float rep[128];
  int tid = threadIdx.x;
  if (tid < 128) rep[tid] = repsum[tid] * (1.0f / (float)NN);
  __syncthreads();
  if (tid < 10) {
    float a = hb[tid];
#pragma unroll
    for (int c = 0; c < 128; c++) a = fmaf(rep[c], hW[c * 10 + tid], a);
    out[tid] = a;
  }
}

// ---------------- launch ----------------------------------------------------
extern "C" void kernel_launch(void* const* d_in, const int* in_sizes, int n_in,
                              void* d_out, int out_size, void* d_ws, size_t ws_size,
                              hipStream_t stream) {
  const float* x      = (const float*)d_in[0];
  const int*   ei     = (const int*)d_in[1];
  const float* u      = (const float*)d_in[2];
  const float* enc_W0 = (const float*)d_in[3];
  const float* enc_b0 = (const float*)d_in[4];
  const float* enc_W  = (const float*)d_in[5];
  const float* enc_b  = (const float*)d_in[6];
  const float* ea_W1  = (const float*)d_in[7];
  const float* ea_b1  = (const float*)d_in[8];
  const float* ea_W2  = (const float*)d_in[9];
  const float* ea_b2  = (const float*)d_in[10];
  const float* cls_W0 = (const float*)d_in[11];
  const float* cls_b0 = (const float*)d_in[12];
  const float* cls_W  = (const float*)d_in[13];
  const float* cls_b  = (const float*)d_in[14];
  const float* head_W = (const float*)d_in[15];
  const float* head_b = (const float*)d_in[16];
  const int* src  = ei;
  const int* dstp = ei + EE;

  float* wsF = (float*)d_ws;
  int*   wsI = (int*)d_ws;
  int* deg  = wsI + OFF_DEG;
  int* rs   = wsI + OFF_RS;
  int* cur  = wsI + OFF_CUR;
  int* eix  = wsI + OFF_EIX;
  int* gsrc = wsI + OFF_GSRC;
  ushort* B0 = (ushort*)(wsF + OFF_B0);
  ushort* B1 = (ushort*)(wsF + OFF_B1);
  ushort* Pa = (ushort*)(wsF + OFF_PA);
  ushort* Pb = (ushort*)(wsF + OFF_PB);
  float* pe   = wsF + OFF_PE;
  float* dl   = wsF + OFF_DL;
  float* Ta   = wsF + OFF_TT;
  float* hist = wsF + OFF_HIST;
  float* scal = wsF + OFF_SCAL;
  float* rep  = wsF + OFF_REP;
  ushort* Wt  = (ushort*)(wsF + OFF_WT);
  float* out = (float*)d_out;

  init_ws<<<(NN + 255) / 256, 256, 0, stream>>>(deg, cur, hist, scal, rep);
  count_deg<<<(EE + 255) / 256, 256, 0, stream>>>(dstp, deg);
  scan_deg<<<1, 1024, 0, stream>>>(deg, rs);
  fill_csr<<<(EE + 255) / 256, 256, 0, stream>>>(src, dstp, rs, cur, eix, gsrc);
  transpose_all<<<1088, 256, 0, stream>>>(enc_W0, enc_W, cls_W0, cls_W, ea_W1, Wt);

  const int GB = NN / 32;  // 625

  // encoder GIN stack (att = 1): x -> B0 -> B1 -> B0 -> B1 -> B0
  fused_layer64<false><<<GB, 256, 0, stream>>>(x, B0, gsrc, rs, nullptr, Wt + WT_ENC0, enc_b0);
  {
    ushort* in = B0; ushort* outb = B1;
    for (int l = 0; l < 4; l++) {
      fused_layer128<false><<<GB, 256, 0, stream>>>(in, outb, gsrc, rs, nullptr,
                                                    Wt + WT_ENC + (size_t)l * 16384,
                                                    enc_b + (size_t)l * 128);
      ushort* t = in; in = outb; outb = t;
    }
  }
  // encoder output is in B0

  gemm_papb<<<dim3(8, GB), 256, 0, stream>>>(B0, Wt + WT_EA1, ea_b1, Pa, Pb);
  edge_pe_csr<<<(NN + 3) / 4, 256, 0, stream>>>(Pa, Pb, gsrc, rs, ea_W2, ea_b2, pe);

  pe_stats<<<512, 256, 0, stream>>>(pe, scal);
  edge_delta_hist<<<128, 256, 0, stream>>>(pe, u, eix, dl, hist, scal);
  sinkhorn_iter<<<1, 64, 0, stream>>>(hist, scal);
  compute_T<<<(EE + 255) / 256, 256, 0, stream>>>(dl, scal, Ta);

  // classifier GIN stack (att = T, CSR-ordered)
  fused_layer64<true><<<GB, 256, 0, stream>>>(x, B0, gsrc, rs, Ta, Wt + WT_CLS0, cls_b0);
  {
    ushort* in = B0; ushort* outb = B1;
    for (int l = 0; l < 4; l++) {
      fused_layer128<true><<<GB, 256, 0, stream>>>(in, outb, gsrc, rs, Ta,
                                                   Wt + WT_CLS + (size_t)l * 16384,
                                                   cls_b + (size_t)l * 128);
      ushort* t = in; in = outb; outb = t;
    }
  }

  col_mean<<<256, 128, 0, stream>>>(B0, rep);
  head_kernel<<<1, 128, 0, stream>>>(rep, head_W, head_b, out);
}

// Round 5
// 609.310 us; speedup vs baseline: 2.1185x; 1.2292x over previous
//
#include <hip/hip_runtime.h>
#include <math.h>

#define NN 20000
#define EE 320000
#define NBINS 2048
#define HRANGE 64.0f
#define EPSF 1e-20f

typedef __attribute__((ext_vector_type(8))) short bf16x8;
typedef __attribute__((ext_vector_type(4))) float f32x4;

// ---------------- workspace layout (f32-slot offsets, all 16B-aligned) -----
constexpr size_t OFF_DEG  = 0;                    // NN ints
constexpr size_t OFF_RS   = 20000;                // NN+1 ints (+pad)
constexpr size_t OFF_CUR  = 40008;                // NN ints
constexpr size_t OFF_EIX  = 60008;                // EE ints
constexpr size_t OFF_GSRC = 380008;               // EE ints
constexpr size_t OFF_B0   = 700008;               // NN*128 bf16 (1280000 slots)
constexpr size_t OFF_B1   = 1980008;              // NN*128 bf16
constexpr size_t OFF_PA   = 3260008;              // NN*512 bf16
constexpr size_t OFF_PB   = 8380008;              // NN*512 bf16
constexpr size_t OFF_PE   = 13500008;             // EE f32 (CSR order)
constexpr size_t OFF_DL   = 13820008;             // EE f32 (CSR order)
constexpr size_t OFF_TT   = 14140008;             // EE f32 (CSR order)
constexpr size_t OFF_HIST = 14460008;             // 2*NBINS f32
constexpr size_t OFF_SCAL = 14464104;             // 32 f32
constexpr size_t OFF_REP  = 14464136;             // 128 f32
constexpr size_t OFF_WT   = 14464264;             // 278528 bf16
// WT sub-offsets (bf16 units):
constexpr size_t WT_ENC0 = 0;         // 128x64 (n-major)
constexpr size_t WT_ENC  = 8192;      // 4 x 128x128
constexpr size_t WT_CLS0 = 73728;     // 128x64
constexpr size_t WT_CLS  = 81920;     // 4 x 128x128
constexpr size_t WT_EA1  = 147456;    // 512x256

__device__ __forceinline__ unsigned ordf(float f) {
  unsigned b = __float_as_uint(f);
  return (b >> 31) ? ~b : (b | 0x80000000u);
}
__device__ __forceinline__ float unordf(unsigned u) {
  unsigned b = (u >> 31) ? (u ^ 0x80000000u) : ~u;
  return __uint_as_float(b);
}
__device__ __forceinline__ ushort f2bf(float f) {   // RNE
  unsigned u = __float_as_uint(f);
  u += 0x7FFFu + ((u >> 16) & 1u);
  return (ushort)(u >> 16);
}
__device__ __forceinline__ unsigned pack2(float x, float y) {
  return (unsigned)f2bf(x) | ((unsigned)f2bf(y) << 16);
}
__device__ __forceinline__ float bf2f(ushort h) {
  return __uint_as_float(((unsigned)h) << 16);
}
__device__ __forceinline__ float bflo(unsigned v) { return __uint_as_float(v << 16); }
__device__ __forceinline__ float bfhi(unsigned v) { return __uint_as_float(v & 0xFFFF0000u); }

// ---------------- init ------------------------------------------------------
__global__ void init_ws(int* deg, int* cur, float* hist, float* scal, float* rep) {
  int i = blockIdx.x * blockDim.x + threadIdx.x;
  if (i < NN) { deg[i] = 0; cur[i] = 0; }
  if (i < 2 * NBINS) hist[i] = 0.f;
  if (i < 128) rep[i] = 0.f;
  if (i < 32) {
    if (i == 2)      ((unsigned*)scal)[2] = 0xFFFFFFFFu;
    else if (i == 3) ((unsigned*)scal)[3] = 0u;
    else scal[i] = 0.f;
  }
}

// ---------------- CSR build -------------------------------------------------
__global__ void count_deg(const int* __restrict__ dst, int* __restrict__ deg) {
  int e = blockIdx.x * 256 + threadIdx.x;
  if (e < EE) atomicAdd(&deg[dst[e]], 1);
}

__global__ __launch_bounds__(1024) void scan_deg(const int* __restrict__ deg,
                                                 int* __restrict__ rs) {
  __shared__ int ps[1024];
  const int t = threadIdx.x;
  const int base = t * 20;
  int loc[20];
  int s = 0;
#pragma unroll
  for (int j = 0; j < 20; ++j) {
    int idx = base + j;
    int v = (idx < NN) ? deg[idx] : 0;
    loc[j] = s;
    s += v;
  }
  ps[t] = s;
  __syncthreads();
  for (int off = 1; off < 1024; off <<= 1) {
    int x = (t >= off) ? ps[t - off] : 0;
    __syncthreads();
    ps[t] += x;
    __syncthreads();
  }
  const int excl = ps[t] - s;
#pragma unroll
  for (int j = 0; j < 20; ++j) {
    int idx = base + j;
    if (idx < NN) rs[idx] = excl + loc[j];
  }
  if (t == 1023) rs[NN] = ps[1023];
}

__global__ void fill_csr(const int* __restrict__ src, const int* __restrict__ dst,
                         const int* __restrict__ rs, int* __restrict__ cur,
                         int* __restrict__ eidx, int* __restrict__ gsrc) {
  int e = blockIdx.x * 256 + threadIdx.x;
  if (e < EE) {
    int d = dst[e];
    int p = atomicAdd(&cur[d], 1);
    int o = rs[d] + p;
    eidx[o] = e;
    gsrc[o] = src[e];
  }
}

// ---------------- all weight transposes in one kernel -----------------------
__global__ void transpose_all(const float* __restrict__ encW0, const float* __restrict__ encW,
                              const float* __restrict__ clsW0, const float* __restrict__ clsW,
                              const float* __restrict__ eaW1, ushort* __restrict__ Wt) {
  int i = blockIdx.x * 256 + threadIdx.x;
  if (i < 8192) {                       // enc_W0: 64x128 -> [n][k]
    int k = i >> 7, n = i & 127;
    Wt[WT_ENC0 + n * 64 + k] = f2bf(encW0[i]);
  } else if (i < 73728) {               // enc_W: 4 x 128x128
    int j = i - 8192;
    int l = j >> 14, r = j & 16383, k = r >> 7, n = r & 127;
    Wt[WT_ENC + l * 16384 + n * 128 + k] = f2bf(encW[j]);
  } else if (i < 81920) {               // cls_W0
    int j = i - 73728;
    int k = j >> 7, n = j & 127;
    Wt[WT_CLS0 + n * 64 + k] = f2bf(clsW0[j]);
  } else if (i < 147456) {              // cls_W
    int j = i - 81920;
    int l = j >> 14, r = j & 16383, k = r >> 7, n = r & 127;
    Wt[WT_CLS + l * 16384 + n * 128 + k] = f2bf(clsW[j]);
  } else if (i < 278528) {              // ea_W1: 256x512 -> [n][k]
    int j = i - 147456;
    int k = j >> 9, n = j & 511;
    Wt[WT_EA1 + n * 256 + k] = f2bf(eaW1[j]);
  }
}

// ---------------- fused GIN layer, K=64 (fp32 x in, bf16 out) ---------------
// 256 thr = 32 groups of 8 lanes; one independent gather chain per node.
// depth-2 prefetch, 2 float4 loads per edge per lane.
template <bool HASATT>
__global__ __launch_bounds__(256) void fused_layer64(
    const float* __restrict__ X, ushort* __restrict__ C,
    const int* __restrict__ gsrc, const int* __restrict__ rs,
    const float* __restrict__ att, const ushort* __restrict__ Bt,
    const float* __restrict__ bias) {
  __shared__ __align__(16) char smem[16896];
  ushort* Asm = (ushort*)smem;                 // [32][80] stride 80 bf16 (160B)
  const int tid = threadIdx.x;
  const int g = tid >> 3, l = tid & 7;
  const int nb = blockIdx.x * 32;
  {
    const int n = nb + g;
    const int e0 = rs[n], e1 = rs[n + 1];
    const float4* Xr = (const float4*)(X + (size_t)n * 64);
    float4 s0 = Xr[l * 2], s1 = Xr[l * 2 + 1];
    float a[8] = {s0.x, s0.y, s0.z, s0.w, s1.x, s1.y, s1.z, s1.w};
    int i = e0;
    float4 c0, c1, d0, d1;
    float cw = 1.f, dw = 1.f;
    if (i < e1) {
      const float4* R = (const float4*)(X + (size_t)gsrc[i] * 64);
      if (HASATT) cw = att[i];
      c0 = R[l * 2]; c1 = R[l * 2 + 1];
    }
    if (i + 1 < e1) {
      const float4* R = (const float4*)(X + (size_t)gsrc[i + 1] * 64);
      if (HASATT) dw = att[i + 1];
      d0 = R[l * 2]; d1 = R[l * 2 + 1];
    }
    while (i < e1) {
      float4 p0, p1;
      float pw = 1.f;
      if (i + 2 < e1) {
        const float4* R = (const float4*)(X + (size_t)gsrc[i + 2] * 64);
        if (HASATT) pw = att[i + 2];
        p0 = R[l * 2]; p1 = R[l * 2 + 1];
      }
      a[0] = fmaf(cw, c0.x, a[0]); a[1] = fmaf(cw, c0.y, a[1]);
      a[2] = fmaf(cw, c0.z, a[2]); a[3] = fmaf(cw, c0.w, a[3]);
      a[4] = fmaf(cw, c1.x, a[4]); a[5] = fmaf(cw, c1.y, a[5]);
      a[6] = fmaf(cw, c1.z, a[6]); a[7] = fmaf(cw, c1.w, a[7]);
      c0 = d0; c1 = d1; cw = dw;
      d0 = p0; d1 = p1; dw = pw;
      ++i;
    }
    uint4 o;
    o.x = pack2(a[0], a[1]); o.y = pack2(a[2], a[3]);
    o.z = pack2(a[4], a[5]); o.w = pack2(a[6], a[7]);
    *(uint4*)(Asm + g * 80 + l * 8) = o;
  }
  __syncthreads();
  const int wave = tid >> 6, lane = tid & 63, quad = lane >> 4, l15 = lane & 15;
  const int mh = wave >> 1, nh = wave & 1;
  f32x4 acc[4] = {{0.f, 0.f, 0.f, 0.f}, {0.f, 0.f, 0.f, 0.f},
                  {0.f, 0.f, 0.f, 0.f}, {0.f, 0.f, 0.f, 0.f}};
#pragma unroll
  for (int k0 = 0; k0 < 64; k0 += 32) {
    bf16x8 af = *(const bf16x8*)(Asm + (mh * 16 + l15) * 80 + k0 + quad * 8);
#pragma unroll
    for (int t = 0; t < 4; ++t) {
      int bn = nh * 64 + t * 16 + l15;
      bf16x8 bf = *(const bf16x8*)(Bt + (size_t)bn * 64 + k0 + quad * 8);
      acc[t] = __builtin_amdgcn_mfma_f32_16x16x32_bf16(af, bf, acc[t], 0, 0, 0);
    }
  }
  __syncthreads();
  float (*Csm)[132] = (float(*)[132])smem;
#pragma unroll
  for (int t = 0; t < 4; ++t) {
    int lc = nh * 64 + t * 16 + l15;
    float bs = bias[lc];
#pragma unroll
    for (int r = 0; r < 4; ++r)
      Csm[mh * 16 + quad * 4 + r][lc] = fmaxf(acc[t][r] + bs, 0.f);
  }
  __syncthreads();
  const int r = tid >> 3, c0 = (tid & 7) * 16;
  ushort* Cp = C + (size_t)(nb + r) * 128 + c0;
#pragma unroll
  for (int k = 0; k < 4; ++k) {
    f32x4 vv = *(const f32x4*)&Csm[r][c0 + k * 4];
    ushort4 o;
    o.x = f2bf(vv[0]); o.y = f2bf(vv[1]); o.z = f2bf(vv[2]); o.w = f2bf(vv[3]);
    *(ushort4*)(Cp + k * 4) = o;
  }
}

// ---------------- fused GIN layer, K=128 (bf16 in/out) ----------------------
// 32 groups of 8 lanes; 2 uint4 (32B) per edge per lane; depth-2 prefetch.
template <bool HASATT>
__global__ __launch_bounds__(256) void fused_layer128(
    const ushort* __restrict__ Xb, ushort* __restrict__ C,
    const int* __restrict__ gsrc, const int* __restrict__ rs,
    const float* __restrict__ att, const ushort* __restrict__ Bt,
    const float* __restrict__ bias) {
  __shared__ __align__(16) char smem[16896];
  ushort* Asm = (ushort*)smem;                 // [32][136] stride 136 bf16 (272B)
  const int tid = threadIdx.x;
  const int g = tid >> 3, l = tid & 7;
  const int nb = blockIdx.x * 32;
  {
    const int n = nb + g;
    const int e0 = rs[n], e1 = rs[n + 1];
    float a[16];
    {
      const uint4* Xr = (const uint4*)(Xb + (size_t)n * 128);
      uint4 s0 = Xr[l * 2], s1 = Xr[l * 2 + 1];
      a[0] = bflo(s0.x); a[1] = bfhi(s0.x); a[2] = bflo(s0.y); a[3] = bfhi(s0.y);
      a[4] = bflo(s0.z); a[5] = bfhi(s0.z); a[6] = bflo(s0.w); a[7] = bfhi(s0.w);
      a[8] = bflo(s1.x); a[9] = bfhi(s1.x); a[10] = bflo(s1.y); a[11] = bfhi(s1.y);
      a[12] = bflo(s1.z); a[13] = bfhi(s1.z); a[14] = bflo(s1.w); a[15] = bfhi(s1.w);
    }
    int i = e0;
    uint4 c0, c1, d0, d1;
    float cw = 1.f, dw = 1.f;
    if (i < e1) {
      const uint4* R = (const uint4*)(Xb + (size_t)gsrc[i] * 128);
      if (HASATT) cw = att[i];
      c0 = R[l * 2]; c1 = R[l * 2 + 1];
    }
    if (i + 1 < e1) {
      const uint4* R = (const uint4*)(Xb + (size_t)gsrc[i + 1] * 128);
      if (HASATT) dw = att[i + 1];
      d0 = R[l * 2]; d1 = R[l * 2 + 1];
    }
    while (i < e1) {
      uint4 p0, p1;
      float pw = 1.f;
      if (i + 2 < e1) {
        const uint4* R = (const uint4*)(Xb + (size_t)gsrc[i + 2] * 128);
        if (HASATT) pw = att[i + 2];
        p0 = R[l * 2]; p1 = R[l * 2 + 1];
      }
      a[0] = fmaf(cw, bflo(c0.x), a[0]);  a[1] = fmaf(cw, bfhi(c0.x), a[1]);
      a[2] = fmaf(cw, bflo(c0.y), a[2]);  a[3] = fmaf(cw, bfhi(c0.y), a[3]);
      a[4] = fmaf(cw, bflo(c0.z), a[4]);  a[5] = fmaf(cw, bfhi(c0.z), a[5]);
      a[6] = fmaf(cw, bflo(c0.w), a[6]);  a[7] = fmaf(cw, bfhi(c0.w), a[7]);
      a[8] = fmaf(cw, bflo(c1.x), a[8]);  a[9] = fmaf(cw, bfhi(c1.x), a[9]);
      a[10] = fmaf(cw, bflo(c1.y), a[10]); a[11] = fmaf(cw, bfhi(c1.y), a[11]);
      a[12] = fmaf(cw, bflo(c1.z), a[12]); a[13] = fmaf(cw, bfhi(c1.z), a[13]);
      a[14] = fmaf(cw, bflo(c1.w), a[14]); a[15] = fmaf(cw, bfhi(c1.w), a[15]);
      c0 = d0; c1 = d1; cw = dw;
      d0 = p0; d1 = p1; dw = pw;
      ++i;
    }
    uint4 o0, o1;
    o0.x = pack2(a[0], a[1]); o0.y = pack2(a[2], a[3]);
    o0.z = pack2(a[4], a[5]); o0.w = pack2(a[6], a[7]);
    o1.x = pack2(a[8], a[9]); o1.y = pack2(a[10], a[11]);
    o1.z = pack2(a[12], a[13]); o1.w = pack2(a[14], a[15]);
    *(uint4*)(Asm + g * 136 + l * 16) = o0;
    *(uint4*)(Asm + g * 136 + l * 16 + 8) = o1;
  }
  __syncthreads();
  const int wave = tid >> 6, lane = tid & 63, quad = lane >> 4, l15 = lane & 15;
  const int mh = wave >> 1, nh = wave & 1;
  f32x4 acc[4] = {{0.f, 0.f, 0.f, 0.f}, {0.f, 0.f, 0.f, 0.f},
                  {0.f, 0.f, 0.f, 0.f}, {0.f, 0.f, 0.f, 0.f}};
#pragma unroll
  for (int k0 = 0; k0 < 128; k0 += 32) {
    bf16x8 af = *(const bf16x8*)(Asm + (mh * 16 + l15) * 136 + k0 + quad * 8);
#pragma unroll
    for (int t = 0; t < 4; ++t) {
      int bn = nh * 64 + t * 16 + l15;
      bf16x8 bf = *(const bf16x8*)(Bt + (size_t)bn * 128 + k0 + quad * 8);
      acc[t] = __builtin_amdgcn_mfma_f32_16x16x32_bf16(af, bf, acc[t], 0, 0, 0);
    }
  }
  __syncthreads();
  float (*Csm)[132] = (float(*)[132])smem;
#pragma unroll
  for (int t = 0; t < 4; ++t) {
    int lc = nh * 64 + t * 16 + l15;
    float bs = bias[lc];
#pragma unroll
    for (int r = 0; r < 4; ++r)
      Csm[mh * 16 + quad * 4 + r][lc] = fmaxf(acc[t][r] + bs, 0.f);
  }
  __syncthreads();
  const int r = tid >> 3, c0 = (tid & 7) * 16;
  ushort* Cp = C + (size_t)(nb + r) * 128 + c0;
#pragma unroll
  for (int k = 0; k < 4; ++k) {
    f32x4 vv = *(const f32x4*)&Csm[r][c0 + k * 4];
    ushort4 o;
    o.x = f2bf(vv[0]); o.y = f2bf(vv[1]); o.z = f2bf(vv[2]); o.w = f2bf(vv[3]);
    *(ushort4*)(Cp + k * 4) = o;
  }
}

// ---------------- Pa/Pb in one launch: grid (8, 625) ------------------------
__global__ __launch_bounds__(256) void gemm_papb(
    const ushort* __restrict__ Hb, const ushort* __restrict__ W1t,
    const float* __restrict__ b1, ushort* __restrict__ Pa, ushort* __restrict__ Pb) {
  __shared__ float lds[32][132];
  const int tid = threadIdx.x;
  const int wave = tid >> 6, lane = tid & 63, quad = lane >> 4, l15 = lane & 15;
  const int mh = wave >> 1, nh = wave & 1;
  const bool isB = blockIdx.x >= 4;
  const int col0 = (blockIdx.x & 3) * 128;
  const int row0 = blockIdx.y * 32;
  const ushort* Bt = W1t + (isB ? 128 : 0);
  ushort* C = isB ? Pb : Pa;
  f32x4 acc[4] = {{0.f, 0.f, 0.f, 0.f}, {0.f, 0.f, 0.f, 0.f},
                  {0.f, 0.f, 0.f, 0.f}, {0.f, 0.f, 0.f, 0.f}};
  const ushort* Ap = Hb + (size_t)(row0 + mh * 16 + l15) * 128 + quad * 8;
#pragma unroll
  for (int k0 = 0; k0 < 128; k0 += 32) {
    bf16x8 af = *(const bf16x8*)(Ap + k0);
#pragma unroll
    for (int t = 0; t < 4; ++t) {
      int bn = col0 + nh * 64 + t * 16 + l15;
      bf16x8 bf = *(const bf16x8*)(Bt + (size_t)bn * 256 + k0 + quad * 8);
      acc[t] = __builtin_amdgcn_mfma_f32_16x16x32_bf16(af, bf, acc[t], 0, 0, 0);
    }
  }
#pragma unroll
  for (int t = 0; t < 4; ++t) {
    int lc = nh * 64 + t * 16 + l15;
    float bs = isB ? 0.f : b1[col0 + lc];
#pragma unroll
    for (int r = 0; r < 4; ++r)
      lds[mh * 16 + quad * 4 + r][lc] = acc[t][r] + bs;
  }
  __syncthreads();
  const int r = tid >> 3, c0 = (tid & 7) * 16;
  ushort* Cp = C + (size_t)(row0 + r) * 512 + col0 + c0;
#pragma unroll
  for (int k = 0; k < 4; ++k) {
    f32x4 v = *(const f32x4*)&lds[r][c0 + k * 4];
    ushort4 o;
    o.x = f2bf(v[0]); o.y = f2bf(v[1]); o.z = f2bf(v[2]); o.w = f2bf(v[3]);
    *(ushort4*)(Cp + k * 4) = o;
  }
}

// ---------------- edge MLP layer 2: 32-lane half-wave chains ----------------
// Each half-wave (32 lanes) owns one dst node; 2 uint4 per edge per lane.
__global__ __launch_bounds__(256) void edge_pe_csr(
    const ushort* __restrict__ Pa, const ushort* __restrict__ Pb,
    const int* __restrict__ gsrc, const int* __restrict__ rs,
    const float* __restrict__ W2, const float* __restrict__ b2,
    float* __restrict__ pe) {
  const int tid = threadIdx.x;
  const int lane = tid & 63;
  const int hl = lane & 31;
  const int n = blockIdx.x * 8 + (tid >> 5);
  if (n >= NN) return;
  const int e0 = rs[n], e1 = rs[n + 1];
  if (e0 == e1) return;
  float w[16], pb[16];
  {
    const float4* w2v = (const float4*)(W2 + hl * 16);
#pragma unroll
    for (int q = 0; q < 4; ++q) {
      float4 t = w2v[q];
      w[q * 4 + 0] = t.x; w[q * 4 + 1] = t.y; w[q * 4 + 2] = t.z; w[q * 4 + 3] = t.w;
    }
    const uint4* pbr = (const uint4*)(Pb + (size_t)n * 512);
    uint4 b0 = pbr[hl * 2], b1 = pbr[hl * 2 + 1];
    pb[0] = bflo(b0.x); pb[1] = bfhi(b0.x); pb[2] = bflo(b0.y); pb[3] = bfhi(b0.y);
    pb[4] = bflo(b0.z); pb[5] = bfhi(b0.z); pb[6] = bflo(b0.w); pb[7] = bfhi(b0.w);
    pb[8] = bflo(b1.x); pb[9] = bfhi(b1.x); pb[10] = bflo(b1.y); pb[11] = bfhi(b1.y);
    pb[12] = bflo(b1.z); pb[13] = bfhi(b1.z); pb[14] = bflo(b1.w); pb[15] = bfhi(b1.w);
  }
  const float b2v = b2[0];
  int i = e0;
  uint4 c0, c1, d0, d1;
  {
    const uint4* R = (const uint4*)(Pa + (size_t)gsrc[i] * 512);
    c0 = R[hl * 2]; c1 = R[hl * 2 + 1];
  }
  if (i + 1 < e1) {
    const uint4* R = (const uint4*)(Pa + (size_t)gsrc[i + 1] * 512);
    d0 = R[hl * 2]; d1 = R[hl * 2 + 1];
  }
  while (i < e1) {
    uint4 p0, p1;
    if (i + 2 < e1) {
      const uint4* R = (const uint4*)(Pa + (size_t)gsrc[i + 2] * 512);
      p0 = R[hl * 2]; p1 = R[hl * 2 + 1];
    }
    float pa[16] = {bflo(c0.x), bfhi(c0.x), bflo(c0.y), bfhi(c0.y),
                    bflo(c0.z), bfhi(c0.z), bflo(c0.w), bfhi(c0.w),
                    bflo(c1.x), bfhi(c1.x), bflo(c1.y), bfhi(c1.y),
                    bflo(c1.z), bfhi(c1.z), bflo(c1.w), bfhi(c1.w)};
    float acc = 0.f;
#pragma unroll
    for (int j = 0; j < 16; ++j) acc += fmaxf(pa[j] + pb[j], 0.f) * w[j];
#pragma unroll
    for (int off = 16; off; off >>= 1) acc += __shfl_xor(acc, off);
    if (hl == 0) pe[i] = acc + b2v;
    c0 = d0; c1 = d1;
    d0 = p0; d1 = p1;
    ++i;
  }
}

// ---------------- pe statistics (sum, sumsq, min, max) ----------------------
__global__ __launch_bounds__(256) void pe_stats(const float* __restrict__ pe,
                                                float* __restrict__ scal) {
  __shared__ float r1[256], r2[256], r3[256], r4[256];
  int tid = threadIdx.x;
  float s = 0.f, q = 0.f, mn = 3.0e38f, mx = -3.0e38f;
  for (int i = blockIdx.x * 256 + tid; i < EE; i += gridDim.x * 256) {
    float v = pe[i];
    s += v; q = fmaf(v, v, q);
    mn = fminf(mn, v); mx = fmaxf(mx, v);
  }
  r1[tid] = s; r2[tid] = q; r3[tid] = mn; r4[tid] = mx;
  __syncthreads();
  for (int k = 128; k > 0; k >>= 1) {
    if (tid < k) {
      r1[tid] += r1[tid + k];
      r2[tid] += r2[tid + k];
      r3[tid] = fminf(r3[tid], r3[tid + k]);
      r4[tid] = fmaxf(r4[tid], r4[tid + k]);
    }
    __syncthreads();
  }
  if (tid == 0) {
    unsafeAtomicAdd(&scal[0], r1[0]);
    unsafeAtomicAdd(&scal[1], r2[0]);
    atomicMin((unsigned*)scal + 2, ordf(r3[0]));
    atomicMax((unsigned*)scal + 3, ordf(r4[0]));
  }
}

// ---------------- delta + histogram (CSR order; u gathered via eidx) --------
__global__ __launch_bounds__(256) void edge_delta_hist(
    const float* __restrict__ pe, const float* __restrict__ u,
    const int* __restrict__ eidx, float* __restrict__ delta,
    float* __restrict__ hist, const float* __restrict__ scal) {
  __shared__ float cnt_s[NBINS], sum_s[NBINS];
  for (int b = threadIdx.x; b < NBINS; b += 256) { cnt_s[b] = 0.f; sum_s[b] = 0.f; }
  float sum = scal[0], ssq = scal[1];
  float mn = unordf(((const unsigned*)scal)[2]);
  float mx = unordf(((const unsigned*)scal)[3]);
  float mu = sum / (float)EE;
  float var = (ssq - sum * sum / (float)EE) / (float)(EE - 1);
  float istd = rsqrtf(fmaxf(var, 1e-30f));
  float shift = (mn - mu) * istd + (mx - mu) * istd;
  __syncthreads();
  for (int i = blockIdx.x * 256 + threadIdx.x; i < EE; i += gridDim.x * 256) {
    float uu = u[eidx[i]];
    float atts = (pe[i] - mu) * istd;
    float g = -logf(-logf(uu + EPSF) + EPSF);
    float dl = 2.0f * (atts + g) - shift;
    delta[i] = dl;
    float dcl = fminf(fmaxf(dl, -HRANGE), HRANGE * 0.9999f);
    int b = (int)((dcl + HRANGE) * ((float)NBINS / (2.0f * HRANGE)));
    b = min(max(b, 0), NBINS - 1);
    atomicAdd(&cnt_s[b], 1.0f);
    atomicAdd(&sum_s[b], dcl);
  }
  __syncthreads();
  for (int b = threadIdx.x; b < NBINS; b += 256) {
    float c = cnt_s[b];
    if (c != 0.f) {
      unsafeAtomicAdd(&hist[b], c);
      unsafeAtomicAdd(&hist[NBINS + b], sum_s[b]);
    }
  }
}

// ---------------- scalar Sinkhorn recursion (single wave) -------------------
__global__ __launch_bounds__(64) void sinkhorn_iter(const float* __restrict__ hist,
                                                    float* __restrict__ scal) {
  const int lane = threadIdx.x;
  float cnt[32], mean[32];
#pragma unroll
  for (int b = 0; b < 32; ++b) {
    int idx = b * 64 + lane;
    float c = hist[idx];
    cnt[b] = c;
    mean[b] = (c > 0.f) ? hist[NBINS + idx] / c : 0.f;
  }
  const float LRD = -1.0986122886681098f;
  float S = 0.f, Zfin = 0.f;
  for (int it = 0; it < 30; ++it) {
    float p = 0.f;
#pragma unroll
    for (int b = 0; b < 32; ++b)
      if (cnt[b] > 0.f) p += cnt[b] / (1.f + expf(-(mean[b] + S)));
#pragma unroll
    for (int off = 32; off; off >>= 1) p += __shfl_xor(p, off);
    if (it < 29)
      S += logf(fmaxf((float)EE - p, 1.0f)) - logf(p) + LRD;
    else
      Zfin = p;
  }
  if (lane == 0) {
    scal[8] = S;
    scal[9] = ((float)EE * 0.25f) / Zfin;
  }
}

// ---------------- T_i (CSR order) -------------------------------------------
__global__ void compute_T(const float* __restrict__ delta,
                          const float* __restrict__ scal,
                          float* __restrict__ Ta) {
  int i = blockIdx.x * 256 + threadIdx.x;
  if (i >= EE) return;
  float S = scal[8], sc = scal[9];
  Ta[i] = sc / (1.f + expf(-(delta[i] + S)));
}

// ---------------- mean pooling (4 independent partials) + head --------------
__global__ __launch_bounds__(128) void col_mean(const ushort* __restrict__ Hc,
                                                float* __restrict__ rep) {
  int c = threadIdx.x;
  const int g = gridDim.x;
  float p0 = 0.f, p1 = 0.f, p2 = 0.f, p3 = 0.f;
  int n = blockIdx.x;
  for (; n + 3 * g < NN; n += 4 * g) {
    p0 += bf2f(Hc[(size_t)n * 128 + c]);
    p1 += bf2f(Hc[(size_t)(n + g) * 128 + c]);
    p2 += bf2f(Hc[(size_t)(n + 2 * g) * 128 + c]);
    p3 += bf2f(Hc[(size_t)(n + 3 * g) * 128 + c]);
  }
  for (; n < NN; n += g) p0 += bf2f(Hc[(size_t)n * 128 + c]);
  unsafeAtomicAdd(&rep[c], (p0 + p1) + (p2 + p3));
}

__global__ __launch_bounds__(128) void head_kernel(const float* __restrict__ repsum,
                                                   const float* __restrict__ hW,
                                                   const float* __restrict__ hb,
                                                   float* __restrict__ out) {
  __shared__ float rep[128];
  int tid = threadIdx.x;
  if (tid < 128) rep[tid] = repsum[tid] * (1.0f / (float)NN);
  __syncthreads();
  if (tid < 10) {
    float a = hb[tid];
#pragma unroll
    for (int c = 0; c < 128; c++) a = fmaf(rep[c], hW[c * 10 + tid], a);
    out[tid] = a;
  }
}

// ---------------- launch ----------------------------------------------------
extern "C" void kernel_launch(void* const* d_in, const int* in_sizes, int n_in,
                              void* d_out, int out_size, void* d_ws, size_t ws_size,
                              hipStream_t stream) {
  const float* x      = (const float*)d_in[0];
  const int*   ei     = (const int*)d_in[1];
  const float* u      = (const float*)d_in[2];
  const float* enc_W0 = (const float*)d_in[3];
  const float* enc_b0 = (const float*)d_in[4];
  const float* enc_W  = (const float*)d_in[5];
  const float* enc_b  = (const float*)d_in[6];
  const float* ea_W1  = (const float*)d_in[7];
  const float* ea_b1  = (const float*)d_in[8];
  const float* ea_W2  = (const float*)d_in[9];
  const float* ea_b2  = (const float*)d_in[10];
  const float* cls_W0 = (const float*)d_in[11];
  const float* cls_b0 = (const float*)d_in[12];
  const float* cls_W  = (const float*)d_in[13];
  const float* cls_b  = (const float*)d_in[14];
  const float* head_W = (const float*)d_in[15];
  const float* head_b = (const float*)d_in[16];
  const int* src  = ei;
  const int* dstp = ei + EE;

  float* wsF = (float*)d_ws;
  int*   wsI = (int*)d_ws;
  int* deg  = wsI + OFF_DEG;
  int* rs   = wsI + OFF_RS;
  int* cur  = wsI + OFF_CUR;
  int* eix  = wsI + OFF_EIX;
  int* gsrc = wsI + OFF_GSRC;
  ushort* B0 = (ushort*)(wsF + OFF_B0);
  ushort* B1 = (ushort*)(wsF + OFF_B1);
  ushort* Pa = (ushort*)(wsF + OFF_PA);
  ushort* Pb = (ushort*)(wsF + OFF_PB);
  float* pe   = wsF + OFF_PE;
  float* dl   = wsF + OFF_DL;
  float* Ta   = wsF + OFF_TT;
  float* hist = wsF + OFF_HIST;
  float* scal = wsF + OFF_SCAL;
  float* rep  = wsF + OFF_REP;
  ushort* Wt  = (ushort*)(wsF + OFF_WT);
  float* out = (float*)d_out;

  init_ws<<<(NN + 255) / 256, 256, 0, stream>>>(deg, cur, hist, scal, rep);
  count_deg<<<(EE + 255) / 256, 256, 0, stream>>>(dstp, deg);
  scan_deg<<<1, 1024, 0, stream>>>(deg, rs);
  fill_csr<<<(EE + 255) / 256, 256, 0, stream>>>(src, dstp, rs, cur, eix, gsrc);
  transpose_all<<<1088, 256, 0, stream>>>(enc_W0, enc_W, cls_W0, cls_W, ea_W1, Wt);

  const int GB = NN / 32;  // 625

  // encoder GIN stack (att = 1)
  fused_layer64<false><<<GB, 256, 0, stream>>>(x, B0, gsrc, rs, nullptr, Wt + WT_ENC0, enc_b0);
  {
    ushort* in = B0; ushort* outb = B1;
    for (int l = 0; l < 4; l++) {
      fused_layer128<false><<<GB, 256, 0, stream>>>(in, outb, gsrc, rs, nullptr,
                                                    Wt + WT_ENC + (size_t)l * 16384,
                                                    enc_b + (size_t)l * 128);
      ushort* t = in; in = outb; outb = t;
    }
  }
  // encoder output in B0

  gemm_papb<<<dim3(8, GB), 256, 0, stream>>>(B0, Wt + WT_EA1, ea_b1, Pa, Pb);
  edge_pe_csr<<<NN / 8, 256, 0, stream>>>(Pa, Pb, gsrc, rs, ea_W2, ea_b2, pe);

  pe_stats<<<512, 256, 0, stream>>>(pe, scal);
  edge_delta_hist<<<128, 256, 0, stream>>>(pe, u, eix, dl, hist, scal);
  sinkhorn_iter<<<1, 64, 0, stream>>>(hist, scal);
  compute_T<<<(EE + 255) / 256, 256, 0, stream>>>(dl, scal, Ta);

  // classifier GIN stack (att = T, CSR-ordered)
  fused_layer64<true><<<GB, 256, 0, stream>>>(x, B0, gsrc, rs, Ta, Wt + WT_CLS0, cls_b0);
  {
    ushort* in = B0; ushort* outb = B1;
    for (int l = 0; l < 4; l++) {
      fused_layer128<true><<<GB, 256, 0, stream>>>(in, outb, gsrc, rs, Ta,
                                                   Wt + WT_CLS + (size_t)l * 16384,
                                                   cls_b + (size_t)l * 128);
      ushort* t = in; in = outb; outb = t;
    }
  }

  col_mean<<<256, 128, 0, stream>>>(B0, rep);
  head_kernel<<<1, 128, 0, stream>>>(rep, head_W, head_b, out);
}